// Round 5
// baseline (390.602 us; speedup 1.0000x reference)
//
#include <hip/hip_runtime.h>
#include <hip/hip_bf16.h>
#include <stdint.h>

#define DIM   1024
#define HEADS 16
#define KVH   4
#define HD    64
#define SEQ   2048
#define BATCH 2
#define MTOT  (BATCH*SEQ)   // 4096

// 0.125 (= HD^-0.5) * log2(e): Q is pre-scaled so softmax uses exp2 directly.
#define QSCALE 0.18033688011112042f

typedef __attribute__((ext_vector_type(8)))  short v8s;    // 8 bf16 (4 VGPRs)
typedef __attribute__((ext_vector_type(4)))  float v4f;    // 16x16 accumulator
typedef __attribute__((ext_vector_type(16))) float f32x16; // 32x32 accumulator

static __device__ __forceinline__ short f2bf(float v) {
    __hip_bfloat16 h = __float2bfloat16(v);
    return *reinterpret_cast<short*>(&h);
}

// ---------------- f32 -> bf16 convert (vectorized) ----------------
__global__ __launch_bounds__(256) void k_cvt(const float* __restrict__ in,
                                             short* __restrict__ out, int n4) {
    int i = blockIdx.x * 256 + threadIdx.x;
    if (i >= n4) return;
    float4 v = reinterpret_cast<const float4*>(in)[i];
    short4 o;
    o.x = f2bf(v.x); o.y = f2bf(v.y); o.z = f2bf(v.z); o.w = f2bf(v.w);
    reinterpret_cast<short4*>(out)[i] = o;
}

// ---------------- W [rows][cols] f32 -> Wt [cols][rows] bf16 ----------------
__global__ __launch_bounds__(256) void k_transpose_w(const float* __restrict__ W,
                                                     short* __restrict__ Wt,
                                                     int rows, int cols) {
    __shared__ float tile[32][33];
    int c0 = blockIdx.x * 32, r0 = blockIdx.y * 32;
    int tx = threadIdx.x & 31;
    int ty = threadIdx.x >> 5;        // 0..7
#pragma unroll
    for (int i = 0; i < 4; ++i)
        tile[ty + i*8][tx] = W[(size_t)(r0 + ty + i*8) * cols + c0 + tx];
    __syncthreads();
#pragma unroll
    for (int i = 0; i < 4; ++i)
        Wt[(size_t)(c0 + ty + i*8) * rows + r0 + tx] = f2bf(tile[tx][ty + i*8]);
}

// ---------------- GEMM: C[M][Nout] = A[M][K] * Bt[Nout][K]^T + bias ----------------
// MODE 1: out f32 row-major [M][Nout]                        (O-projection)
// MODE 2: out bf16 V^T: addr ((col>>11)*256 + grow)*2048 + (col&2047), bias1[grow]
// MODE 3: fused Q+K: col<1024 -> Q [b][h][n][64] * QSCALE (bias1);
//                    col>=1024 -> K [b][kvh][n][64] (bias2); K block at +4194304 elems
template<int MODE>
__global__ __launch_bounds__(256)
void k_gemm(const short* __restrict__ A, const short* __restrict__ Bt,
            const float* __restrict__ bias1, const float* __restrict__ bias2,
            void* __restrict__ Cout, int K, int Nout) {
    __shared__ short As[128 * 64];
    __shared__ short Bs[128 * 64];
    const int tid  = threadIdx.x;
    const int lane = tid & 63;
    const int wave = tid >> 6;
    const int bm = blockIdx.x * 128;
    const int bn = blockIdx.y * 128;
    const int wm = (wave >> 1) * 64;
    const int wn = (wave & 1) * 64;
    const int lo = lane & 15, hi = lane >> 4;
    v4f acc[4][4] = {};
    const int nkt = K >> 6;
    for (int kt = 0; kt < nkt; ++kt) {
        __syncthreads();
#pragma unroll
        for (int i = 0; i < 4; ++i) {
            int c = i * 256 + tid;
            int row = c >> 3, col = c & 7;
            int4 va = *reinterpret_cast<const int4*>(A  + (size_t)(bm + row) * K + kt*64 + col*8);
            *reinterpret_cast<int4*>(reinterpret_cast<char*>(As) + row*128 + ((col*16) ^ ((row & 7) << 4))) = va;
            int4 vb = *reinterpret_cast<const int4*>(Bt + (size_t)(bn + row) * K + kt*64 + col*8);
            *reinterpret_cast<int4*>(reinterpret_cast<char*>(Bs) + row*128 + ((col*16) ^ ((row & 7) << 4))) = vb;
        }
        __syncthreads();
#pragma unroll
        for (int ks = 0; ks < 2; ++ks) {
            v8s af[4], bfr[4];
#pragma unroll
            for (int mf = 0; mf < 4; ++mf) {
                int row = wm + mf*16 + lo;
                af[mf] = *reinterpret_cast<const v8s*>(reinterpret_cast<const char*>(As)
                           + row*128 + ((ks*64 + hi*16) ^ ((row & 7) << 4)));
            }
#pragma unroll
            for (int nf = 0; nf < 4; ++nf) {
                int row = wn + nf*16 + lo;
                bfr[nf] = *reinterpret_cast<const v8s*>(reinterpret_cast<const char*>(Bs)
                           + row*128 + ((ks*64 + hi*16) ^ ((row & 7) << 4)));
            }
#pragma unroll
            for (int mf = 0; mf < 4; ++mf)
#pragma unroll
                for (int nf = 0; nf < 4; ++nf)
                    acc[mf][nf] = __builtin_amdgcn_mfma_f32_16x16x32_bf16(af[mf], bfr[nf], acc[mf][nf], 0, 0, 0);
        }
    }
    // epilogue: C/D layout col=lane&15, row=(lane>>4)*4+reg
#pragma unroll
    for (int nf = 0; nf < 4; ++nf) {
        int col = bn + wn + nf*16 + lo;
#pragma unroll
        for (int mf = 0; mf < 4; ++mf) {
#pragma unroll
            for (int j = 0; j < 4; ++j) {
                int grow = bm + wm + mf*16 + hi*4 + j;
                float acv = acc[mf][nf][j];
                if (MODE == 1) {
                    reinterpret_cast<float*>(Cout)[(size_t)grow * Nout + col] = acv + bias1[col];
                } else if (MODE == 2) {
                    // grow = kvh*64+d in [0,256); col = b*2048+n
                    float val = acv + bias1[grow];
                    reinterpret_cast<short*>(Cout)[((size_t)(col >> 11) * 256 + grow) * 2048 + (col & 2047)] = f2bf(val);
                } else { // MODE 3
                    int b = grow >> 11, n = grow & 2047;
                    if (col < 1024) {
                        int hh = col >> 6, d = col & 63;
                        float val = (acv + bias1[col]) * QSCALE;
                        reinterpret_cast<short*>(Cout)[((size_t)(b * HEADS + hh) * SEQ + n) * HD + d] = f2bf(val);
                    } else {
                        int cc = col - 1024;
                        int kvh = cc >> 6, d = cc & 63;
                        float val = acv + bias2[cc];
                        reinterpret_cast<short*>(Cout)[4194304 + ((size_t)(b * KVH + kvh) * SEQ + n) * HD + d] = f2bf(val);
                    }
                }
            }
        }
    }
}

// ---------------- flash attention, swapped-operand, in-block KV-split x4 ----------------
// Grid: 2048 blocks x 256 threads (4 waves). Each block: 32 q-rows of one (b,h);
// wave w covers kv range [w*512, (w+1)*512) = 16 tiles of 32 kv.
// S^T = K.Q^T via mfma_32x32x16 (A=K, B=Q): C col = q = lane&31 (lane-local q),
// row = kv = (reg&3)+8*(reg>>2)+4*(lane>>5). O^T = V^T.P^T: C col = q again ->
// online-softmax state (m, l) and the split-merge weight are pure per-lane scalars.
// Epilogue: in-LDS merge of the 4 partials (exact f32 flash-merge), no global scratch.
__global__ __launch_bounds__(256, 8)
void k_attn(const short* __restrict__ Q, const short* __restrict__ K,
            const short* __restrict__ Vt, short* __restrict__ AO) {
    const int tid  = threadIdx.x;
    const int lane = tid & 63;
    const int wave = tid >> 6;              // KV-split index 0..3
    const int l31 = lane & 31, hi2 = (lane >> 5) & 1;
    const int id  = blockIdx.x;
    const int g   = id & 7;                 // (b, kvh) group -> XCD locality
    const int b   = g >> 2, kvh = g & 3;
    const int idx = id >> 3;                // 0..255
    const int h   = kvh * 4 + (idx >> 6);   // GQA: heads 4k..4k+3 share kv-head k
    const int q0  = (idx & 63) * 32;

    const short* Qb = Q  + ((size_t)(b * HEADS + h) * SEQ + q0) * HD;
    const short* Kb = K  + (size_t)(b * KVH + kvh) * SEQ * HD;
    const short* Vb = Vt + (size_t)(b * KVH + kvh) * HD * SEQ;   // [64 d][2048 n]

    // Q fragments (B-operand): col q = l31, k(d) = 16c + 8*hi2 + j
    v8s qf[4];
#pragma unroll
    for (int c = 0; c < 4; ++c)
        qf[c] = *reinterpret_cast<const v8s*>(Qb + (size_t)l31 * HD + c * 16 + hi2 * 8);

    f32x16 acc0 = {}, acc1 = {};   // O^T rows d 0-31 / 32-63, col q = l31
    float mrun = -1e30f, lsum = 0.f;

    const int kt0 = wave * (SEQ / 32 / 4);
    for (int kt = kt0; kt < kt0 + SEQ / 32 / 4; ++kt) {
        const short* Kt = Kb + (size_t)kt * 32 * HD;
        f32x16 s = {};
#pragma unroll
        for (int c = 0; c < 4; ++c) {
            v8s kf = *reinterpret_cast<const v8s*>(Kt + (size_t)l31 * HD + c * 16 + hi2 * 8);
            s = __builtin_amdgcn_mfma_f32_32x32x16_bf16(kf, qf[c], s, 0, 0, 0);
        }
        // max over this tile's 32 kv (16 in-lane + cross-half)
        float m0 = fmaxf(fmaxf(s[0],  s[1]),  fmaxf(s[2],  s[3]));
        float m1 = fmaxf(fmaxf(s[4],  s[5]),  fmaxf(s[6],  s[7]));
        float m2 = fmaxf(fmaxf(s[8],  s[9]),  fmaxf(s[10], s[11]));
        float m3 = fmaxf(fmaxf(s[12], s[13]), fmaxf(s[14], s[15]));
        float pmax = fmaxf(fmaxf(m0, m1), fmaxf(m2, m3));
        pmax = fmaxf(pmax, __shfl_xor(pmax, 32));
        // defer-max (T13): only rescale when max grew by > 8 (log2 domain)
        if (!__all(pmax <= mrun + 8.f)) {
            float mnew = fmaxf(mrun, pmax);
            float sc = exp2f(mrun - mnew);
#pragma unroll
            for (int r = 0; r < 16; ++r) { acc0[r] *= sc; acc1[r] *= sc; }
            lsum *= sc;
            mrun = mnew;
        }
#pragma unroll
        for (int r = 0; r < 16; ++r) s[r] = exp2f(s[r] - mrun);   // p in-place
        float a0 = (s[0] + s[1]) + (s[2]  + s[3]);
        float a1 = (s[4] + s[5]) + (s[6]  + s[7]);
        float a2 = (s[8] + s[9]) + (s[10] + s[11]);
        float a3 = (s[12]+ s[13])+ (s[14] + s[15]);
        float ls = (a0 + a1) + (a2 + a3);
        lsum += ls + __shfl_xor(ls, 32);

        // pack p -> bf16 pairs; pk_i = (p[2i] low, p[2i+1] high)
        int pk[8];
#pragma unroll
        for (int i = 0; i < 8; ++i) {
            int r;
            asm("v_cvt_pk_bf16_f32 %0, %1, %2" : "=v"(r) : "v"(s[2*i]), "v"(s[2*i+1]));
            pk[i] = r;
        }
        // half-exchange: B-operand slot j must hold kv = 16*kc + 8*hi2 + j
        int u[8];
#pragma unroll
        for (int i = 0; i < 2; ++i) {
            int p0 = pk[4*i+0], p1 = pk[4*i+1], p2 = pk[4*i+2], p3 = pk[4*i+3];
            int o0 = __shfl_xor(p0, 32), o1 = __shfl_xor(p1, 32);
            int o2 = __shfl_xor(p2, 32), o3 = __shfl_xor(p3, 32);
            u[4*i+0] = hi2 ? o2 : p0;
            u[4*i+1] = hi2 ? o3 : p1;
            u[4*i+2] = hi2 ? p2 : o0;
            u[4*i+3] = hi2 ? p3 : o1;
        }
        union { int i4[4]; v8s v; } pb0, pb1;
        pb0.i4[0] = u[0]; pb0.i4[1] = u[1]; pb0.i4[2] = u[2]; pb0.i4[3] = u[3];
        pb1.i4[0] = u[4]; pb1.i4[1] = u[5]; pb1.i4[2] = u[6]; pb1.i4[3] = u[7];

        // O^T += V^T-chunk . P^T   (A row = d = lane&31, k = kv = 8*hi2+j)
        const short* Vtt = Vb + kt * 32;
        {
            v8s vf0 = *reinterpret_cast<const v8s*>(Vtt + (size_t)l31        * SEQ + hi2 * 8);
            acc0 = __builtin_amdgcn_mfma_f32_32x32x16_bf16(vf0, pb0.v, acc0, 0, 0, 0);
            v8s vf1 = *reinterpret_cast<const v8s*>(Vtt + (size_t)(32 + l31) * SEQ + hi2 * 8);
            acc1 = __builtin_amdgcn_mfma_f32_32x32x16_bf16(vf1, pb0.v, acc1, 0, 0, 0);
            v8s vf2 = *reinterpret_cast<const v8s*>(Vtt + (size_t)l31        * SEQ + 16 + hi2 * 8);
            acc0 = __builtin_amdgcn_mfma_f32_32x32x16_bf16(vf2, pb1.v, acc0, 0, 0, 0);
            v8s vf3 = *reinterpret_cast<const v8s*>(Vtt + (size_t)(32 + l31) * SEQ + 16 + hi2 * 8);
            acc1 = __builtin_amdgcn_mfma_f32_32x32x16_bf16(vf3, pb1.v, acc1, 0, 0, 0);
        }
    }

    // ---- in-block flash-merge of the 4 KV-split partials (exact f32) ----
    __shared__ float mlS[4][2][32];   // [wave][m,l][q]
    __shared__ float obuf[64][32];    // merged O^T [d][q]
    if (hi2 == 0) { mlS[wave][0][l31] = mrun; mlS[wave][1][l31] = lsum; }
    __syncthreads();
    {
        float w0 = mlS[0][0][l31], w1 = mlS[1][0][l31];
        float w2 = mlS[2][0][l31], w3 = mlS[3][0][l31];
        float mstar = fmaxf(fmaxf(w0, w1), fmaxf(w2, w3));
        float myw = exp2f(mrun - mstar);          // lane-local: q = l31
#pragma unroll
        for (int r = 0; r < 16; ++r) { acc0[r] *= myw; acc1[r] *= myw; }
    }
    // sequential accumulate into obuf (wave-uniform branch, 4 barriers)
    for (int ws = 0; ws < 4; ++ws) {
        if (wave == ws) {
#pragma unroll
            for (int rg = 0; rg < 4; ++rg)
#pragma unroll
                for (int i = 0; i < 4; ++i) {
                    int d = rg*8 + hi2*4 + i;
                    if (ws == 0) {
                        obuf[d][l31]      = acc0[rg*4+i];
                        obuf[d+32][l31]   = acc1[rg*4+i];
                    } else {
                        obuf[d][l31]     += acc0[rg*4+i];
                        obuf[d+32][l31]  += acc1[rg*4+i];
                    }
                }
        }
        __syncthreads();
    }
    // output: thread -> q = tid>>3 (0..31), d0 = (tid&7)*8; coalesced 16B stores
    {
        int q = tid >> 3, d0 = (tid & 7) * 8;
        float mm0 = mlS[0][0][q], mm1 = mlS[1][0][q];
        float mm2 = mlS[2][0][q], mm3 = mlS[3][0][q];
        float ms = fmaxf(fmaxf(mm0, mm1), fmaxf(mm2, mm3));
        float lstar = exp2f(mm0 - ms) * mlS[0][1][q] + exp2f(mm1 - ms) * mlS[1][1][q]
                    + exp2f(mm2 - ms) * mlS[2][1][q] + exp2f(mm3 - ms) * mlS[3][1][q];
        float rinv = 1.f / lstar;
        union { short s[8]; int4 v; } o8;
#pragma unroll
        for (int i = 0; i < 8; ++i) o8.s[i] = f2bf(obuf[d0 + i][q] * rinv);
        short* Ao = AO + ((size_t)(b * SEQ + q0 + q)) * DIM + h * HD + d0;
        *reinterpret_cast<int4*>(Ao) = o8.v;
    }
}

extern "C" void kernel_launch(void* const* d_in, const int* in_sizes, int n_in,
                              void* d_out, int out_size, void* d_ws, size_t ws_size,
                              hipStream_t stream) {
    const float* x  = (const float*)d_in[0];
    const float* Wq = (const float*)d_in[1];
    const float* bq = (const float*)d_in[2];
    const float* Wk = (const float*)d_in[3];
    const float* bk = (const float*)d_in[4];
    const float* Wv = (const float*)d_in[5];
    const float* bv = (const float*)d_in[6];
    const float* Wo = (const float*)d_in[7];
    const float* bo = (const float*)d_in[8];
    float* out = (float*)d_out;

    char* w = (char*)d_ws;
    size_t off = 0;
    auto alloc = [&](size_t bytes) { void* p = w + off; off += (bytes + 255) & ~(size_t)255; return p; };
    short* xb   = (short*)alloc((size_t)MTOT * DIM * 2);           // x bf16
    short* WqkT = (short*)alloc((size_t)(DIM + KVH*HD) * DIM * 2); // [1280][1024]
    short* WvT  = (short*)alloc((size_t)(KVH*HD) * DIM * 2);       // [256][1024]
    short* WoT  = (short*)alloc((size_t)DIM * DIM * 2);
    short* QK   = (short*)alloc((size_t)(BATCH*HEADS*SEQ*HD + BATCH*KVH*SEQ*HD) * 2); // Q then K
    short* VtG  = (short*)alloc((size_t)BATCH * KVH * HD * SEQ * 2); // V^T [b][kvh*64+d][n]
    short* AO   = (short*)alloc((size_t)MTOT * DIM * 2);           // attn out [B][N][H*D]

    short* Qh = QK;
    short* Kh = QK + (size_t)BATCH * HEADS * SEQ * HD;  // == QK + 4194304

    k_cvt<<<dim3((MTOT * DIM / 4 + 255) / 256), dim3(256), 0, stream>>>(x, xb, MTOT * DIM / 4);
    k_transpose_w<<<dim3(DIM/32,      DIM/32), dim3(256), 0, stream>>>(Wq, WqkT,             DIM, DIM);
    k_transpose_w<<<dim3((KVH*HD)/32, DIM/32), dim3(256), 0, stream>>>(Wk, WqkT + DIM*DIM,   DIM, KVH*HD);
    k_transpose_w<<<dim3((KVH*HD)/32, DIM/32), dim3(256), 0, stream>>>(Wv, WvT,              DIM, KVH*HD);
    k_transpose_w<<<dim3(DIM/32,      DIM/32), dim3(256), 0, stream>>>(Wo, WoT,              DIM, DIM);

    // fused Q+K projection (Nout = 1280)
    k_gemm<3><<<dim3(MTOT/128, (DIM + KVH*HD)/128), dim3(256), 0, stream>>>(
        xb, WqkT, bq, bk, (void*)QK, DIM, DIM + KVH*HD);
    // V^T = Wv^T . x^T  (M=256, N=4096) — emits V already transposed
    k_gemm<2><<<dim3((KVH*HD)/128, MTOT/128), dim3(256), 0, stream>>>(
        WvT, xb, bv, nullptr, (void*)VtG, DIM, MTOT);

    // one block per (b, h, 32-row q-tile): 2*16*64 = 2048 blocks, 4 waves each (KV-split)
    k_attn<<<dim3(BATCH * HEADS * (SEQ/32)), dim3(256), 0, stream>>>(Qh, Kh, VtG, AO);

    k_gemm<1><<<dim3(MTOT/128, DIM/128), dim3(256), 0, stream>>>(
        AO, WoT, bo, nullptr, (void*)out, DIM, DIM);
}

// Round 6
// 293.632 us; speedup vs baseline: 1.3302x; 1.3302x over previous
//
#include <hip/hip_runtime.h>
#include <hip/hip_bf16.h>
#include <stdint.h>

#define DIM   1024
#define HEADS 16
#define KVH   4
#define HD    64
#define SEQ   2048
#define BATCH 2
#define MTOT  (BATCH*SEQ)   // 4096

// 0.125 (= HD^-0.5) * log2(e): Q is pre-scaled so softmax uses exp2 directly.
#define QSCALE 0.18033688011112042f

typedef __attribute__((ext_vector_type(8)))  short v8s;    // 8 bf16 (4 VGPRs)
typedef __attribute__((ext_vector_type(4)))  float v4f;    // 16x16 accumulator
typedef __attribute__((ext_vector_type(16))) float f32x16; // 32x32 accumulator

static __device__ __forceinline__ short f2bf(float v) {
    __hip_bfloat16 h = __float2bfloat16(v);
    return *reinterpret_cast<short*>(&h);
}

// ---------------- f32 -> bf16 convert (vectorized) ----------------
__global__ __launch_bounds__(256) void k_cvt(const float* __restrict__ in,
                                             short* __restrict__ out, int n4) {
    int i = blockIdx.x * 256 + threadIdx.x;
    if (i >= n4) return;
    float4 v = reinterpret_cast<const float4*>(in)[i];
    short4 o;
    o.x = f2bf(v.x); o.y = f2bf(v.y); o.z = f2bf(v.z); o.w = f2bf(v.w);
    reinterpret_cast<short4*>(out)[i] = o;
}

// ---------------- W [rows][cols] f32 -> Wt [cols][rows] bf16 ----------------
__global__ __launch_bounds__(256) void k_transpose_w(const float* __restrict__ W,
                                                     short* __restrict__ Wt,
                                                     int rows, int cols) {
    __shared__ float tile[32][33];
    int c0 = blockIdx.x * 32, r0 = blockIdx.y * 32;
    int tx = threadIdx.x & 31;
    int ty = threadIdx.x >> 5;        // 0..7
#pragma unroll
    for (int i = 0; i < 4; ++i)
        tile[ty + i*8][tx] = W[(size_t)(r0 + ty + i*8) * cols + c0 + tx];
    __syncthreads();
#pragma unroll
    for (int i = 0; i < 4; ++i)
        Wt[(size_t)(c0 + ty + i*8) * rows + r0 + tx] = f2bf(tile[tx][ty + i*8]);
}

// ---------------- GEMM: C[M][Nout] = A[M][K] * Bt[Nout][K]^T + bias ----------------
// MODE 1: out f32 row-major [M][Nout]                        (O-projection)
// MODE 2: out bf16 V^T: addr ((col>>11)*256 + grow)*2048 + (col&2047), bias1[grow]
// MODE 3: fused Q+K: col<1024 -> Q [b][h][n][64] * QSCALE (bias1);
//                    col>=1024 -> K [b][kvh][n][64] (bias2); K block at +4194304 elems
template<int MODE>
__global__ __launch_bounds__(256)
void k_gemm(const short* __restrict__ A, const short* __restrict__ Bt,
            const float* __restrict__ bias1, const float* __restrict__ bias2,
            void* __restrict__ Cout, int K, int Nout) {
    __shared__ short As[128 * 64];
    __shared__ short Bs[128 * 64];
    const int tid  = threadIdx.x;
    const int lane = tid & 63;
    const int wave = tid >> 6;
    const int bm = blockIdx.x * 128;
    const int bn = blockIdx.y * 128;
    const int wm = (wave >> 1) * 64;
    const int wn = (wave & 1) * 64;
    const int lo = lane & 15, hi = lane >> 4;
    v4f acc[4][4] = {};
    const int nkt = K >> 6;
    for (int kt = 0; kt < nkt; ++kt) {
        __syncthreads();
#pragma unroll
        for (int i = 0; i < 4; ++i) {
            int c = i * 256 + tid;
            int row = c >> 3, col = c & 7;
            int4 va = *reinterpret_cast<const int4*>(A  + (size_t)(bm + row) * K + kt*64 + col*8);
            *reinterpret_cast<int4*>(reinterpret_cast<char*>(As) + row*128 + ((col*16) ^ ((row & 7) << 4))) = va;
            int4 vb = *reinterpret_cast<const int4*>(Bt + (size_t)(bn + row) * K + kt*64 + col*8);
            *reinterpret_cast<int4*>(reinterpret_cast<char*>(Bs) + row*128 + ((col*16) ^ ((row & 7) << 4))) = vb;
        }
        __syncthreads();
#pragma unroll
        for (int ks = 0; ks < 2; ++ks) {
            v8s af[4], bfr[4];
#pragma unroll
            for (int mf = 0; mf < 4; ++mf) {
                int row = wm + mf*16 + lo;
                af[mf] = *reinterpret_cast<const v8s*>(reinterpret_cast<const char*>(As)
                           + row*128 + ((ks*64 + hi*16) ^ ((row & 7) << 4)));
            }
#pragma unroll
            for (int nf = 0; nf < 4; ++nf) {
                int row = wn + nf*16 + lo;
                bfr[nf] = *reinterpret_cast<const v8s*>(reinterpret_cast<const char*>(Bs)
                           + row*128 + ((ks*64 + hi*16) ^ ((row & 7) << 4)));
            }
#pragma unroll
            for (int mf = 0; mf < 4; ++mf)
#pragma unroll
                for (int nf = 0; nf < 4; ++nf)
                    acc[mf][nf] = __builtin_amdgcn_mfma_f32_16x16x32_bf16(af[mf], bfr[nf], acc[mf][nf], 0, 0, 0);
        }
    }
    // epilogue: C/D layout col=lane&15, row=(lane>>4)*4+reg
#pragma unroll
    for (int nf = 0; nf < 4; ++nf) {
        int col = bn + wn + nf*16 + lo;
#pragma unroll
        for (int mf = 0; mf < 4; ++mf) {
#pragma unroll
            for (int j = 0; j < 4; ++j) {
                int grow = bm + wm + mf*16 + hi*4 + j;
                float acv = acc[mf][nf][j];
                if (MODE == 1) {
                    reinterpret_cast<float*>(Cout)[(size_t)grow * Nout + col] = acv + bias1[col];
                } else if (MODE == 2) {
                    // grow = kvh*64+d in [0,256); col = b*2048+n
                    float val = acv + bias1[grow];
                    reinterpret_cast<short*>(Cout)[((size_t)(col >> 11) * 256 + grow) * 2048 + (col & 2047)] = f2bf(val);
                } else { // MODE 3
                    int b = grow >> 11, n = grow & 2047;
                    if (col < 1024) {
                        int hh = col >> 6, d = col & 63;
                        float val = (acv + bias1[col]) * QSCALE;
                        reinterpret_cast<short*>(Cout)[((size_t)(b * HEADS + hh) * SEQ + n) * HD + d] = f2bf(val);
                    } else {
                        int cc = col - 1024;
                        int kvh = cc >> 6, d = cc & 63;
                        float val = acv + bias2[cc];
                        reinterpret_cast<short*>(Cout)[4194304 + ((size_t)(b * KVH + kvh) * SEQ + n) * HD + d] = f2bf(val);
                    }
                }
            }
        }
    }
}

// ---------------- flash attention, swapped-operand, in-block KV-split x4 ----------------
// Grid: 2048 blocks x 256 threads (4 waves). Each block: 32 q-rows of one (b,h);
// wave w covers kv range [w*512, (w+1)*512) = 16 tiles of 32 kv.
// S^T = K.Q^T via mfma_32x32x16 (A=K, B=Q): C col = q = lane&31 (lane-local q),
// row = kv = (reg&3)+8*(reg>>2)+4*(lane>>5). O^T = V^T.P^T: C col = q again ->
// online-softmax state (m, l) and the split-merge weight are pure per-lane scalars.
// Epilogue: in-LDS merge of the 4 partials (exact f32 flash-merge), no global scratch.
// NOTE: min-waves is 4 (VGPR cap 128), NOT 8 — the (256,8) variant capped VGPR at 64
// and spilled the f32x16 accumulators to scratch: 280 MB/dispatch HBM traffic, 235 µs.
__global__ __launch_bounds__(256, 4)
void k_attn(const short* __restrict__ Q, const short* __restrict__ K,
            const short* __restrict__ Vt, short* __restrict__ AO) {
    const int tid  = threadIdx.x;
    const int lane = tid & 63;
    const int wave = tid >> 6;              // KV-split index 0..3
    const int l31 = lane & 31, hi2 = (lane >> 5) & 1;
    const int id  = blockIdx.x;
    const int g   = id & 7;                 // (b, kvh) group -> XCD locality
    const int b   = g >> 2, kvh = g & 3;
    const int idx = id >> 3;                // 0..255
    const int h   = kvh * 4 + (idx >> 6);   // GQA: heads 4k..4k+3 share kv-head k
    const int q0  = (idx & 63) * 32;

    const short* Qb = Q  + ((size_t)(b * HEADS + h) * SEQ + q0) * HD;
    const short* Kb = K  + (size_t)(b * KVH + kvh) * SEQ * HD;
    const short* Vb = Vt + (size_t)(b * KVH + kvh) * HD * SEQ;   // [64 d][2048 n]

    // Q fragments (B-operand): col q = l31, k(d) = 16c + 8*hi2 + j
    v8s qf[4];
#pragma unroll
    for (int c = 0; c < 4; ++c)
        qf[c] = *reinterpret_cast<const v8s*>(Qb + (size_t)l31 * HD + c * 16 + hi2 * 8);

    f32x16 acc0 = {}, acc1 = {};   // O^T rows d 0-31 / 32-63, col q = l31
    float mrun = -1e30f, lsum = 0.f;

    const int kt0 = wave * (SEQ / 32 / 4);
    for (int kt = kt0; kt < kt0 + SEQ / 32 / 4; ++kt) {
        const short* Kt = Kb + (size_t)kt * 32 * HD;
        f32x16 s = {};
#pragma unroll
        for (int c = 0; c < 4; ++c) {
            v8s kf = *reinterpret_cast<const v8s*>(Kt + (size_t)l31 * HD + c * 16 + hi2 * 8);
            s = __builtin_amdgcn_mfma_f32_32x32x16_bf16(kf, qf[c], s, 0, 0, 0);
        }
        // max over this tile's 32 kv (16 in-lane + cross-half)
        float m0 = fmaxf(fmaxf(s[0],  s[1]),  fmaxf(s[2],  s[3]));
        float m1 = fmaxf(fmaxf(s[4],  s[5]),  fmaxf(s[6],  s[7]));
        float m2 = fmaxf(fmaxf(s[8],  s[9]),  fmaxf(s[10], s[11]));
        float m3 = fmaxf(fmaxf(s[12], s[13]), fmaxf(s[14], s[15]));
        float pmax = fmaxf(fmaxf(m0, m1), fmaxf(m2, m3));
        pmax = fmaxf(pmax, __shfl_xor(pmax, 32));
        // defer-max (T13): only rescale when max grew by > 8 (log2 domain)
        if (!__all(pmax <= mrun + 8.f)) {
            float mnew = fmaxf(mrun, pmax);
            float sc = exp2f(mrun - mnew);
#pragma unroll
            for (int r = 0; r < 16; ++r) { acc0[r] *= sc; acc1[r] *= sc; }
            lsum *= sc;
            mrun = mnew;
        }
#pragma unroll
        for (int r = 0; r < 16; ++r) s[r] = exp2f(s[r] - mrun);   // p in-place
        float a0 = (s[0] + s[1]) + (s[2]  + s[3]);
        float a1 = (s[4] + s[5]) + (s[6]  + s[7]);
        float a2 = (s[8] + s[9]) + (s[10] + s[11]);
        float a3 = (s[12]+ s[13])+ (s[14] + s[15]);
        float ls = (a0 + a1) + (a2 + a3);
        lsum += ls + __shfl_xor(ls, 32);

        // pack p -> bf16 pairs; pk_i = (p[2i] low, p[2i+1] high)
        int pk[8];
#pragma unroll
        for (int i = 0; i < 8; ++i) {
            int r;
            asm("v_cvt_pk_bf16_f32 %0, %1, %2" : "=v"(r) : "v"(s[2*i]), "v"(s[2*i+1]));
            pk[i] = r;
        }
        // half-exchange: B-operand slot j must hold kv = 16*kc + 8*hi2 + j
        int u[8];
#pragma unroll
        for (int i = 0; i < 2; ++i) {
            int p0 = pk[4*i+0], p1 = pk[4*i+1], p2 = pk[4*i+2], p3 = pk[4*i+3];
            int o0 = __shfl_xor(p0, 32), o1 = __shfl_xor(p1, 32);
            int o2 = __shfl_xor(p2, 32), o3 = __shfl_xor(p3, 32);
            u[4*i+0] = hi2 ? o2 : p0;
            u[4*i+1] = hi2 ? o3 : p1;
            u[4*i+2] = hi2 ? p2 : o0;
            u[4*i+3] = hi2 ? p3 : o1;
        }
        union { int i4[4]; v8s v; } pb0, pb1;
        pb0.i4[0] = u[0]; pb0.i4[1] = u[1]; pb0.i4[2] = u[2]; pb0.i4[3] = u[3];
        pb1.i4[0] = u[4]; pb1.i4[1] = u[5]; pb1.i4[2] = u[6]; pb1.i4[3] = u[7];

        // O^T += V^T-chunk . P^T   (A row = d = lane&31, k = kv = 8*hi2+j)
        const short* Vtt = Vb + kt * 32;
        {
            v8s vf0 = *reinterpret_cast<const v8s*>(Vtt + (size_t)l31        * SEQ + hi2 * 8);
            acc0 = __builtin_amdgcn_mfma_f32_32x32x16_bf16(vf0, pb0.v, acc0, 0, 0, 0);
            v8s vf1 = *reinterpret_cast<const v8s*>(Vtt + (size_t)(32 + l31) * SEQ + hi2 * 8);
            acc1 = __builtin_amdgcn_mfma_f32_32x32x16_bf16(vf1, pb0.v, acc1, 0, 0, 0);
            v8s vf2 = *reinterpret_cast<const v8s*>(Vtt + (size_t)l31        * SEQ + 16 + hi2 * 8);
            acc0 = __builtin_amdgcn_mfma_f32_32x32x16_bf16(vf2, pb1.v, acc0, 0, 0, 0);
            v8s vf3 = *reinterpret_cast<const v8s*>(Vtt + (size_t)(32 + l31) * SEQ + 16 + hi2 * 8);
            acc1 = __builtin_amdgcn_mfma_f32_32x32x16_bf16(vf3, pb1.v, acc1, 0, 0, 0);
        }
    }

    // ---- in-block flash-merge of the 4 KV-split partials (exact f32) ----
    __shared__ float mlS[4][2][32];   // [wave][m,l][q]
    __shared__ float obuf[64][32];    // merged O^T [d][q]
    if (hi2 == 0) { mlS[wave][0][l31] = mrun; mlS[wave][1][l31] = lsum; }
    __syncthreads();
    {
        float w0 = mlS[0][0][l31], w1 = mlS[1][0][l31];
        float w2 = mlS[2][0][l31], w3 = mlS[3][0][l31];
        float mstar = fmaxf(fmaxf(w0, w1), fmaxf(w2, w3));
        float myw = exp2f(mrun - mstar);          // lane-local: q = l31
#pragma unroll
        for (int r = 0; r < 16; ++r) { acc0[r] *= myw; acc1[r] *= myw; }
    }
    // sequential accumulate into obuf (wave-uniform branch, 4 barriers)
    for (int ws = 0; ws < 4; ++ws) {
        if (wave == ws) {
#pragma unroll
            for (int rg = 0; rg < 4; ++rg)
#pragma unroll
                for (int i = 0; i < 4; ++i) {
                    int d = rg*8 + hi2*4 + i;
                    if (ws == 0) {
                        obuf[d][l31]      = acc0[rg*4+i];
                        obuf[d+32][l31]   = acc1[rg*4+i];
                    } else {
                        obuf[d][l31]     += acc0[rg*4+i];
                        obuf[d+32][l31]  += acc1[rg*4+i];
                    }
                }
        }
        __syncthreads();
    }
    // output: thread -> q = tid>>3 (0..31), d0 = (tid&7)*8; coalesced 16B stores
    {
        int q = tid >> 3, d0 = (tid & 7) * 8;
        float mm0 = mlS[0][0][q], mm1 = mlS[1][0][q];
        float mm2 = mlS[2][0][q], mm3 = mlS[3][0][q];
        float ms = fmaxf(fmaxf(mm0, mm1), fmaxf(mm2, mm3));
        float lstar = exp2f(mm0 - ms) * mlS[0][1][q] + exp2f(mm1 - ms) * mlS[1][1][q]
                    + exp2f(mm2 - ms) * mlS[2][1][q] + exp2f(mm3 - ms) * mlS[3][1][q];
        float rinv = 1.f / lstar;
        union { short s[8]; int4 v; } o8;
#pragma unroll
        for (int i = 0; i < 8; ++i) o8.s[i] = f2bf(obuf[d0 + i][q] * rinv);
        short* Ao = AO + ((size_t)(b * SEQ + q0 + q)) * DIM + h * HD + d0;
        *reinterpret_cast<int4*>(Ao) = o8.v;
    }
}

extern "C" void kernel_launch(void* const* d_in, const int* in_sizes, int n_in,
                              void* d_out, int out_size, void* d_ws, size_t ws_size,
                              hipStream_t stream) {
    const float* x  = (const float*)d_in[0];
    const float* Wq = (const float*)d_in[1];
    const float* bq = (const float*)d_in[2];
    const float* Wk = (const float*)d_in[3];
    const float* bk = (const float*)d_in[4];
    const float* Wv = (const float*)d_in[5];
    const float* bv = (const float*)d_in[6];
    const float* Wo = (const float*)d_in[7];
    const float* bo = (const float*)d_in[8];
    float* out = (float*)d_out;

    char* w = (char*)d_ws;
    size_t off = 0;
    auto alloc = [&](size_t bytes) { void* p = w + off; off += (bytes + 255) & ~(size_t)255; return p; };
    short* xb   = (short*)alloc((size_t)MTOT * DIM * 2);           // x bf16
    short* WqkT = (short*)alloc((size_t)(DIM + KVH*HD) * DIM * 2); // [1280][1024]
    short* WvT  = (short*)alloc((size_t)(KVH*HD) * DIM * 2);       // [256][1024]
    short* WoT  = (short*)alloc((size_t)DIM * DIM * 2);
    short* QK   = (short*)alloc((size_t)(BATCH*HEADS*SEQ*HD + BATCH*KVH*SEQ*HD) * 2); // Q then K
    short* VtG  = (short*)alloc((size_t)BATCH * KVH * HD * SEQ * 2); // V^T [b][kvh*64+d][n]
    short* AO   = (short*)alloc((size_t)MTOT * DIM * 2);           // attn out [B][N][H*D]

    short* Qh = QK;
    short* Kh = QK + (size_t)BATCH * HEADS * SEQ * HD;  // == QK + 4194304

    k_cvt<<<dim3((MTOT * DIM / 4 + 255) / 256), dim3(256), 0, stream>>>(x, xb, MTOT * DIM / 4);
    k_transpose_w<<<dim3(DIM/32,      DIM/32), dim3(256), 0, stream>>>(Wq, WqkT,             DIM, DIM);
    k_transpose_w<<<dim3((KVH*HD)/32, DIM/32), dim3(256), 0, stream>>>(Wk, WqkT + DIM*DIM,   DIM, KVH*HD);
    k_transpose_w<<<dim3((KVH*HD)/32, DIM/32), dim3(256), 0, stream>>>(Wv, WvT,              DIM, KVH*HD);
    k_transpose_w<<<dim3(DIM/32,      DIM/32), dim3(256), 0, stream>>>(Wo, WoT,              DIM, DIM);

    // fused Q+K projection (Nout = 1280)
    k_gemm<3><<<dim3(MTOT/128, (DIM + KVH*HD)/128), dim3(256), 0, stream>>>(
        xb, WqkT, bq, bk, (void*)QK, DIM, DIM + KVH*HD);
    // V^T = Wv^T . x^T  (M=256, N=4096) — emits V already transposed
    k_gemm<2><<<dim3((KVH*HD)/128, MTOT/128), dim3(256), 0, stream>>>(
        WvT, xb, bv, nullptr, (void*)VtG, DIM, MTOT);

    // one block per (b, h, 32-row q-tile): 2*16*64 = 2048 blocks, 4 waves each (KV-split)
    k_attn<<<dim3(BATCH * HEADS * (SEQ/32)), dim3(256), 0, stream>>>(Qh, Kh, VtG, AO);

    k_gemm<1><<<dim3(MTOT/128, DIM/128), dim3(256), 0, stream>>>(
        AO, WoT, bo, nullptr, (void*)out, DIM, DIM);
}

// Round 7
// 242.430 us; speedup vs baseline: 1.6112x; 1.2112x over previous
//
#include <hip/hip_runtime.h>
#include <hip/hip_bf16.h>
#include <stdint.h>

#define DIM   1024
#define HEADS 16
#define KVH   4
#define HD    64
#define SEQ   2048
#define BATCH 2
#define MTOT  (BATCH*SEQ)   // 4096
#define NT    (SEQ/32)      // 64 kv tiles

// 0.125 (= HD^-0.5) * log2(e): Q is pre-scaled so softmax uses exp2 directly.
#define QSCALE 0.18033688011112042f

typedef __attribute__((ext_vector_type(8)))  short v8s;    // 8 bf16 (4 VGPRs)
typedef __attribute__((ext_vector_type(4)))  float v4f;    // 16x16 accumulator
typedef __attribute__((ext_vector_type(16))) float f32x16; // 32x32 accumulator

static __device__ __forceinline__ short f2bf(float v) {
    __hip_bfloat16 h = __float2bfloat16(v);
    return *reinterpret_cast<short*>(&h);
}

static __device__ __forceinline__ void gload_lds16(const void* g, void* l) {
    __builtin_amdgcn_global_load_lds(
        (const __attribute__((address_space(1))) unsigned int*)g,
        (__attribute__((address_space(3))) unsigned int*)l, 16, 0, 0);
}

// ---------------- f32 -> bf16 convert (vectorized) ----------------
__global__ __launch_bounds__(256) void k_cvt(const float* __restrict__ in,
                                             short* __restrict__ out, int n4) {
    int i = blockIdx.x * 256 + threadIdx.x;
    if (i >= n4) return;
    float4 v = reinterpret_cast<const float4*>(in)[i];
    short4 o;
    o.x = f2bf(v.x); o.y = f2bf(v.y); o.z = f2bf(v.z); o.w = f2bf(v.w);
    reinterpret_cast<short4*>(out)[i] = o;
}

// ---------------- W [rows][cols] f32 -> Wt [cols][rows] bf16 ----------------
__global__ __launch_bounds__(256) void k_transpose_w(const float* __restrict__ W,
                                                     short* __restrict__ Wt,
                                                     int rows, int cols) {
    __shared__ float tile[32][33];
    int c0 = blockIdx.x * 32, r0 = blockIdx.y * 32;
    int tx = threadIdx.x & 31;
    int ty = threadIdx.x >> 5;        // 0..7
#pragma unroll
    for (int i = 0; i < 4; ++i)
        tile[ty + i*8][tx] = W[(size_t)(r0 + ty + i*8) * cols + c0 + tx];
    __syncthreads();
#pragma unroll
    for (int i = 0; i < 4; ++i)
        Wt[(size_t)(c0 + ty + i*8) * rows + r0 + tx] = f2bf(tile[tx][ty + i*8]);
}

// ---------------- GEMM: C[M][Nout] = A[M][K] * Bt[Nout][K]^T + bias ----------------
// MODE 1: out f32 row-major [M][Nout]                        (O-projection)
// MODE 2: out bf16 V^T: addr ((col>>11)*256 + grow)*2048 + (col&2047), bias1[grow]
// MODE 3: fused Q+K: col<1024 -> Q [b][h][n][64] * QSCALE (bias1);
//                    col>=1024 -> K [b][kvh][n][64] (bias2); K block at +4194304 elems
template<int MODE>
__global__ __launch_bounds__(256)
void k_gemm(const short* __restrict__ A, const short* __restrict__ Bt,
            const float* __restrict__ bias1, const float* __restrict__ bias2,
            void* __restrict__ Cout, int K, int Nout) {
    __shared__ short As[128 * 64];
    __shared__ short Bs[128 * 64];
    const int tid  = threadIdx.x;
    const int lane = tid & 63;
    const int wave = tid >> 6;
    const int bm = blockIdx.x * 128;
    const int bn = blockIdx.y * 128;
    const int wm = (wave >> 1) * 64;
    const int wn = (wave & 1) * 64;
    const int lo = lane & 15, hi = lane >> 4;
    v4f acc[4][4] = {};
    const int nkt = K >> 6;
    for (int kt = 0; kt < nkt; ++kt) {
        __syncthreads();
#pragma unroll
        for (int i = 0; i < 4; ++i) {
            int c = i * 256 + tid;
            int row = c >> 3, col = c & 7;
            int4 va = *reinterpret_cast<const int4*>(A  + (size_t)(bm + row) * K + kt*64 + col*8);
            *reinterpret_cast<int4*>(reinterpret_cast<char*>(As) + row*128 + ((col*16) ^ ((row & 7) << 4))) = va;
            int4 vb = *reinterpret_cast<const int4*>(Bt + (size_t)(bn + row) * K + kt*64 + col*8);
            *reinterpret_cast<int4*>(reinterpret_cast<char*>(Bs) + row*128 + ((col*16) ^ ((row & 7) << 4))) = vb;
        }
        __syncthreads();
#pragma unroll
        for (int ks = 0; ks < 2; ++ks) {
            v8s af[4], bfr[4];
#pragma unroll
            for (int mf = 0; mf < 4; ++mf) {
                int row = wm + mf*16 + lo;
                af[mf] = *reinterpret_cast<const v8s*>(reinterpret_cast<const char*>(As)
                           + row*128 + ((ks*64 + hi*16) ^ ((row & 7) << 4)));
            }
#pragma unroll
            for (int nf = 0; nf < 4; ++nf) {
                int row = wn + nf*16 + lo;
                bfr[nf] = *reinterpret_cast<const v8s*>(reinterpret_cast<const char*>(Bs)
                           + row*128 + ((ks*64 + hi*16) ^ ((row & 7) << 4)));
            }
#pragma unroll
            for (int mf = 0; mf < 4; ++mf)
#pragma unroll
                for (int nf = 0; nf < 4; ++nf)
                    acc[mf][nf] = __builtin_amdgcn_mfma_f32_16x16x32_bf16(af[mf], bfr[nf], acc[mf][nf], 0, 0, 0);
        }
    }
    // epilogue: C/D layout col=lane&15, row=(lane>>4)*4+reg
#pragma unroll
    for (int nf = 0; nf < 4; ++nf) {
        int col = bn + wn + nf*16 + lo;
#pragma unroll
        for (int mf = 0; mf < 4; ++mf) {
#pragma unroll
            for (int j = 0; j < 4; ++j) {
                int grow = bm + wm + mf*16 + hi*4 + j;
                float acv = acc[mf][nf][j];
                if (MODE == 1) {
                    reinterpret_cast<float*>(Cout)[(size_t)grow * Nout + col] = acv + bias1[col];
                } else if (MODE == 2) {
                    // grow = kvh*64+d in [0,256); col = b*2048+n
                    float val = acv + bias1[grow];
                    reinterpret_cast<short*>(Cout)[((size_t)(col >> 11) * 256 + grow) * 2048 + (col & 2047)] = f2bf(val);
                } else { // MODE 3
                    int b = grow >> 11, n = grow & 2047;
                    if (col < 1024) {
                        int hh = col >> 6, d = col & 63;
                        float val = (acv + bias1[col]) * QSCALE;
                        reinterpret_cast<short*>(Cout)[((size_t)(b * HEADS + hh) * SEQ + n) * HD + d] = f2bf(val);
                    } else {
                        int cc = col - 1024;
                        int kvh = cc >> 6, d = cc & 63;
                        float val = acv + bias2[cc];
                        reinterpret_cast<short*>(Cout)[4194304 + ((size_t)(b * KVH + kvh) * SEQ + n) * HD + d] = f2bf(val);
                    }
                }
            }
        }
    }
}

// ---------------- flash attention: GQA-shared LDS-staged K/V, swapped-operand ----------------
// Grid: 512 blocks (b,kvh,q-tile) x 256 threads. Wave w = head kvh*4+w; all 4 waves
// share the SAME K/V tiles, staged once per block into LDS (double-buffered,
// global_load_lds w=16, coalesced full-line sources). This cuts L2 traffic 8x vs
// per-wave strided global fragment reads (the round-4/6 ~135us plateau).
// Swizzles (rule #21: linear LDS dest => inverse-swizzled SOURCE + swizzled READ):
//   K tile [32 kv][8 slot16]: lds[r][s] = glob[r][s ^ (r&7)]
//   V^T tile [64 d][4 slot16]: lds[d][s] = glob chunk (s ^ ((d>>1)&3))
// Register math (softmax/pack/PV/epilogue) identical to the verified round-4 kernel.
__global__ __launch_bounds__(256, 2)
void k_attn(const short* __restrict__ Q, const short* __restrict__ K,
            const short* __restrict__ Vt, short* __restrict__ AO) {
    __shared__ int4 KbL[2][256];   // 2 x 4KB
    __shared__ int4 VbL[2][256];   // 2 x 4KB
    const int tid  = threadIdx.x;
    const int lane = tid & 63;
    const int w    = tid >> 6;              // wave = head index within GQA group
    const int l31 = lane & 31, hi2 = (lane >> 5) & 1;
    const int id  = blockIdx.x;
    const int g   = id & 7;                 // (b, kvh) group -> XCD locality
    const int b   = g >> 2, kvh = g & 3;
    const int qt  = id >> 3;                // 0..63
    const int h   = kvh * 4 + w;
    const int q0  = qt * 32;

    const char* Kg = (const char*)(K  + (size_t)(b * KVH + kvh) * SEQ * HD);
    const char* Vg = (const char*)(Vt + (size_t)(b * KVH + kvh) * HD * SEQ);
    const short* Qb = Q + ((size_t)(b * HEADS + h) * SEQ + q0) * HD;

    // stage source offsets (bytes), per-lane, inverse-swizzled
    const int krow  = w * 8 + (lane >> 3);          // 0..31
    const int ksrc  = krow * 128 + (((lane & 7) ^ (krow & 7)) << 4);
    const int vd    = w * 16 + (lane >> 2);         // 0..63
    const int vchk  = (lane & 3) ^ ((vd >> 1) & 3);
    const size_t vsrc = (size_t)vd * (SEQ * 2) + (size_t)vchk * 16;

    // Q fragments (B-operand): col q = l31, k(d) = 16c + 8*hi2 + j
    v8s qf[4];
#pragma unroll
    for (int c = 0; c < 4; ++c)
        qf[c] = *reinterpret_cast<const v8s*>(Qb + (size_t)l31 * HD + c * 16 + hi2 * 8);

    f32x16 acc0 = {}, acc1 = {};   // O^T rows d 0-31 / 32-63, col q = l31
    float mrun = -1e30f, lsum = 0.f;

    // prologue: stage tile 0
    gload_lds16(Kg + ksrc,              (char*)KbL[0] + w * 1024);
    gload_lds16(Vg + vsrc,              (char*)VbL[0] + w * 1024);
    __syncthreads();

    int cur = 0;
    for (int kt = 0; kt < NT; ++kt) {
        // issue next tile's stage early (hides under compute; end-barrier drains)
        if (kt + 1 < NT) {
            gload_lds16(Kg + (size_t)(kt + 1) * 4096 + ksrc, (char*)KbL[cur ^ 1] + w * 1024);
            gload_lds16(Vg + vsrc + (size_t)(kt + 1) * 64,   (char*)VbL[cur ^ 1] + w * 1024);
        }
        const char* Kl = (const char*)KbL[cur];
        const char* Vl = (const char*)VbL[cur];

        // S^T = K.Q^T
        f32x16 s = {};
#pragma unroll
        for (int c = 0; c < 4; ++c) {
            v8s kf = *reinterpret_cast<const v8s*>(Kl + l31 * 128 + (((2*c + hi2) ^ (l31 & 7)) << 4));
            s = __builtin_amdgcn_mfma_f32_32x32x16_bf16(kf, qf[c], s, 0, 0, 0);
        }
        // max over this tile's 32 kv (16 in-lane + cross-half)
        float m0 = fmaxf(fmaxf(s[0],  s[1]),  fmaxf(s[2],  s[3]));
        float m1 = fmaxf(fmaxf(s[4],  s[5]),  fmaxf(s[6],  s[7]));
        float m2 = fmaxf(fmaxf(s[8],  s[9]),  fmaxf(s[10], s[11]));
        float m3 = fmaxf(fmaxf(s[12], s[13]), fmaxf(s[14], s[15]));
        float pmax = fmaxf(fmaxf(m0, m1), fmaxf(m2, m3));
        pmax = fmaxf(pmax, __shfl_xor(pmax, 32));
        // defer-max (T13): only rescale when max grew by > 8 (log2 domain)
        if (!__all(pmax <= mrun + 8.f)) {
            float mnew = fmaxf(mrun, pmax);
            float sc = exp2f(mrun - mnew);
#pragma unroll
            for (int r = 0; r < 16; ++r) { acc0[r] *= sc; acc1[r] *= sc; }
            lsum *= sc;
            mrun = mnew;
        }
#pragma unroll
        for (int r = 0; r < 16; ++r) s[r] = exp2f(s[r] - mrun);   // p in-place
        float a0 = (s[0] + s[1]) + (s[2]  + s[3]);
        float a1 = (s[4] + s[5]) + (s[6]  + s[7]);
        float a2 = (s[8] + s[9]) + (s[10] + s[11]);
        float a3 = (s[12]+ s[13])+ (s[14] + s[15]);
        float ls = (a0 + a1) + (a2 + a3);
        lsum += ls + __shfl_xor(ls, 32);

        // pack p -> bf16 pairs; pk_i = (p[2i] low, p[2i+1] high)
        int pk[8];
#pragma unroll
        for (int i = 0; i < 8; ++i) {
            int r;
            asm("v_cvt_pk_bf16_f32 %0, %1, %2" : "=v"(r) : "v"(s[2*i]), "v"(s[2*i+1]));
            pk[i] = r;
        }
        // half-exchange: B-operand slot j must hold kv = 16*kc + 8*hi2 + j
        int u[8];
#pragma unroll
        for (int i = 0; i < 2; ++i) {
            int p0 = pk[4*i+0], p1 = pk[4*i+1], p2 = pk[4*i+2], p3 = pk[4*i+3];
            int o0 = __shfl_xor(p0, 32), o1 = __shfl_xor(p1, 32);
            int o2 = __shfl_xor(p2, 32), o3 = __shfl_xor(p3, 32);
            u[4*i+0] = hi2 ? o2 : p0;
            u[4*i+1] = hi2 ? o3 : p1;
            u[4*i+2] = hi2 ? p2 : o0;
            u[4*i+3] = hi2 ? p3 : o1;
        }
        union { int i4[4]; v8s v; } pb0, pb1;
        pb0.i4[0] = u[0]; pb0.i4[1] = u[1]; pb0.i4[2] = u[2]; pb0.i4[3] = u[3];
        pb1.i4[0] = u[4]; pb1.i4[1] = u[5]; pb1.i4[2] = u[6]; pb1.i4[3] = u[7];

        // O^T += V^T-chunk . P^T  (A row = d, k = kv = 8*hi2+j); chunk g=2*c2+hi2
        const int vx = (l31 >> 1) & 3;  // same for rows l31 and 32+l31
        {
            v8s vf0 = *reinterpret_cast<const v8s*>(Vl + l31 * 64        + ((hi2       ^ vx) << 4));
            acc0 = __builtin_amdgcn_mfma_f32_32x32x16_bf16(vf0, pb0.v, acc0, 0, 0, 0);
            v8s vf1 = *reinterpret_cast<const v8s*>(Vl + (32 + l31) * 64 + ((hi2       ^ vx) << 4));
            acc1 = __builtin_amdgcn_mfma_f32_32x32x16_bf16(vf1, pb0.v, acc1, 0, 0, 0);
            v8s vf2 = *reinterpret_cast<const v8s*>(Vl + l31 * 64        + (((2 + hi2) ^ vx) << 4));
            acc0 = __builtin_amdgcn_mfma_f32_32x32x16_bf16(vf2, pb1.v, acc0, 0, 0, 0);
            v8s vf3 = *reinterpret_cast<const v8s*>(Vl + (32 + l31) * 64 + (((2 + hi2) ^ vx) << 4));
            acc1 = __builtin_amdgcn_mfma_f32_32x32x16_bf16(vf3, pb1.v, acc1, 0, 0, 0);
        }
        __syncthreads();   // drains next-tile stage (hidden under compute) + read-fence
        cur ^= 1;
    }

    // epilogue: lane holds q = q0+l31; d = 8*rg + 4*hi2 + i (+32 for acc1)
    float rinv = 1.f / lsum;
    short* Ao = AO + ((size_t)(b * SEQ + q0 + l31)) * DIM + h * HD;
#pragma unroll
    for (int rg = 0; rg < 4; ++rg) {
        short4 st0, st1;
        st0.x = f2bf(acc0[rg*4+0] * rinv); st0.y = f2bf(acc0[rg*4+1] * rinv);
        st0.z = f2bf(acc0[rg*4+2] * rinv); st0.w = f2bf(acc0[rg*4+3] * rinv);
        *reinterpret_cast<short4*>(Ao + rg*8 + hi2*4) = st0;
        st1.x = f2bf(acc1[rg*4+0] * rinv); st1.y = f2bf(acc1[rg*4+1] * rinv);
        st1.z = f2bf(acc1[rg*4+2] * rinv); st1.w = f2bf(acc1[rg*4+3] * rinv);
        *reinterpret_cast<short4*>(Ao + 32 + rg*8 + hi2*4) = st1;
    }
}

extern "C" void kernel_launch(void* const* d_in, const int* in_sizes, int n_in,
                              void* d_out, int out_size, void* d_ws, size_t ws_size,
                              hipStream_t stream) {
    const float* x  = (const float*)d_in[0];
    const float* Wq = (const float*)d_in[1];
    const float* bq = (const float*)d_in[2];
    const float* Wk = (const float*)d_in[3];
    const float* bk = (const float*)d_in[4];
    const float* Wv = (const float*)d_in[5];
    const float* bv = (const float*)d_in[6];
    const float* Wo = (const float*)d_in[7];
    const float* bo = (const float*)d_in[8];
    float* out = (float*)d_out;

    char* w = (char*)d_ws;
    size_t off = 0;
    auto alloc = [&](size_t bytes) { void* p = w + off; off += (bytes + 255) & ~(size_t)255; return p; };
    short* xb   = (short*)alloc((size_t)MTOT * DIM * 2);           // x bf16
    short* WqkT = (short*)alloc((size_t)(DIM + KVH*HD) * DIM * 2); // [1280][1024]
    short* WvT  = (short*)alloc((size_t)(KVH*HD) * DIM * 2);       // [256][1024]
    short* WoT  = (short*)alloc((size_t)DIM * DIM * 2);
    short* QK   = (short*)alloc((size_t)(BATCH*HEADS*SEQ*HD + BATCH*KVH*SEQ*HD) * 2); // Q then K
    short* VtG  = (short*)alloc((size_t)BATCH * KVH * HD * SEQ * 2); // V^T [b][kvh*64+d][n]
    short* AO   = (short*)alloc((size_t)MTOT * DIM * 2);           // attn out [B][N][H*D]

    short* Qh = QK;
    short* Kh = QK + (size_t)BATCH * HEADS * SEQ * HD;  // == QK + 4194304

    k_cvt<<<dim3((MTOT * DIM / 4 + 255) / 256), dim3(256), 0, stream>>>(x, xb, MTOT * DIM / 4);
    k_transpose_w<<<dim3(DIM/32,      DIM/32), dim3(256), 0, stream>>>(Wq, WqkT,             DIM, DIM);
    k_transpose_w<<<dim3((KVH*HD)/32, DIM/32), dim3(256), 0, stream>>>(Wk, WqkT + DIM*DIM,   DIM, KVH*HD);
    k_transpose_w<<<dim3((KVH*HD)/32, DIM/32), dim3(256), 0, stream>>>(Wv, WvT,              DIM, KVH*HD);
    k_transpose_w<<<dim3(DIM/32,      DIM/32), dim3(256), 0, stream>>>(Wo, WoT,              DIM, DIM);

    // fused Q+K projection (Nout = 1280)
    k_gemm<3><<<dim3(MTOT/128, (DIM + KVH*HD)/128), dim3(256), 0, stream>>>(
        xb, WqkT, bq, bk, (void*)QK, DIM, DIM + KVH*HD);
    // V^T = Wv^T . x^T  (M=256, N=4096) — emits V already transposed
    k_gemm<2><<<dim3((KVH*HD)/128, MTOT/128), dim3(256), 0, stream>>>(
        WvT, xb, bv, nullptr, (void*)VtG, DIM, MTOT);

    // one block per (b, kvh, 32-row q-tile): 2*4*64 = 512 blocks, 4 waves = 4 GQA heads
    k_attn<<<dim3(BATCH * KVH * (SEQ/32)), dim3(256), 0, stream>>>(Qh, Kh, VtG, AO);

    k_gemm<1><<<dim3(MTOT/128, DIM/128), dim3(256), 0, stream>>>(
        AO, WoT, bo, nullptr, (void*)out, DIM, DIM);
}

// Round 8
// 235.415 us; speedup vs baseline: 1.6592x; 1.0298x over previous
//
#include <hip/hip_runtime.h>
#include <hip/hip_bf16.h>
#include <stdint.h>

#define DIM   1024
#define HEADS 16
#define KVH   4
#define HD    64
#define SEQ   2048
#define BATCH 2
#define MTOT  (BATCH*SEQ)   // 4096

// 0.125 (= HD^-0.5) * log2(e): Q is pre-scaled so softmax uses exp2 directly.
#define QSCALE 0.18033688011112042f

typedef __attribute__((ext_vector_type(8)))  short v8s;    // 8 bf16 (4 VGPRs)
typedef __attribute__((ext_vector_type(4)))  float v4f;    // 16x16 accumulator
typedef __attribute__((ext_vector_type(16))) float f32x16; // 32x32 accumulator

static __device__ __forceinline__ short f2bf(float v) {
    __hip_bfloat16 h = __float2bfloat16(v);
    return *reinterpret_cast<short*>(&h);
}

static __device__ __forceinline__ void gload_lds16(const void* g, void* l) {
    __builtin_amdgcn_global_load_lds(
        (const __attribute__((address_space(1))) unsigned int*)g,
        (__attribute__((address_space(3))) unsigned int*)l, 16, 0, 0);
}

// ---------------- f32 -> bf16 convert (vectorized) ----------------
__global__ __launch_bounds__(256) void k_cvt(const float* __restrict__ in,
                                             short* __restrict__ out, int n4) {
    int i = blockIdx.x * 256 + threadIdx.x;
    if (i >= n4) return;
    float4 v = reinterpret_cast<const float4*>(in)[i];
    short4 o;
    o.x = f2bf(v.x); o.y = f2bf(v.y); o.z = f2bf(v.z); o.w = f2bf(v.w);
    reinterpret_cast<short4*>(out)[i] = o;
}

// ---------------- all 4 weight transposes in ONE launch (z picks matrix) ----------------
__global__ __launch_bounds__(256) void k_transpose_all(
        const float* __restrict__ Wq, const float* __restrict__ Wk,
        const float* __restrict__ Wv, const float* __restrict__ Wo,
        short* __restrict__ WqkT, short* __restrict__ WvT, short* __restrict__ WoT) {
    const int z = blockIdx.z;
    const float* W; short* Wt; int rows, cols;
    if      (z == 0) { W = Wq; Wt = WqkT;            rows = DIM; cols = DIM;    }
    else if (z == 1) { W = Wk; Wt = WqkT + DIM*DIM;  rows = DIM; cols = KVH*HD; }
    else if (z == 2) { W = Wv; Wt = WvT;             rows = DIM; cols = KVH*HD; }
    else             { W = Wo; Wt = WoT;             rows = DIM; cols = DIM;    }
    int c0 = blockIdx.x * 32, r0 = blockIdx.y * 32;
    if (c0 >= cols || r0 >= rows) return;
    __shared__ float tile[32][33];
    int tx = threadIdx.x & 31;
    int ty = threadIdx.x >> 5;        // 0..7
#pragma unroll
    for (int i = 0; i < 4; ++i)
        tile[ty + i*8][tx] = W[(size_t)(r0 + ty + i*8) * cols + c0 + tx];
    __syncthreads();
#pragma unroll
    for (int i = 0; i < 4; ++i)
        Wt[(size_t)(c0 + ty + i*8) * rows + r0 + tx] = f2bf(tile[tx][ty + i*8]);
}

// ---------------- GEMM: C[M][Nout] = A[M][K] * Bt[Nout][K]^T + bias ----------------
// Staging via global_load_lds (linear LDS dest = base+lane*16; swizzled layout kept
// by INVERSE-swizzling the global source slot: LDS[row][s] = G[row][s ^ (row&7)]).
// MODE 1: out f32 row-major [M][Nout]                        (O-projection)
// MODE 2: out bf16 V^T: addr ((col>>11)*256 + grow)*2048 + (col&2047), bias1[grow]
// MODE 3: fused Q+K: col<1024 -> Q [b][h][n][64] * QSCALE (bias1);
//                    col>=1024 -> K [b][kvh][n][64] (bias2); K block at +4194304 elems
template<int MODE>
__global__ __launch_bounds__(256)
void k_gemm(const short* __restrict__ A, const short* __restrict__ Bt,
            const float* __restrict__ bias1, const float* __restrict__ bias2,
            void* __restrict__ Cout, int K, int Nout) {
    __shared__ short As[128 * 64];
    __shared__ short Bs[128 * 64];
    const int tid  = threadIdx.x;
    const int lane = tid & 63;
    const int wave = tid >> 6;
    const int bm = blockIdx.x * 128;
    const int bn = blockIdx.y * 128;
    const int wm = (wave >> 1) * 64;
    const int wn = (wave & 1) * 64;
    const int lo = lane & 15, hi = lane >> 4;
    const int l8 = lane & 7, lr = lane >> 3;        // staging: slot, row-within-8
    const int sslot = (l8 ^ lr) << 4;               // inverse-swizzled src slot bytes
    v4f acc[4][4] = {};
    const int nkt = K >> 6;
    for (int kt = 0; kt < nkt; ++kt) {
        __syncthreads();
#pragma unroll
        for (int i = 0; i < 4; ++i) {
            int row = i * 32 + wave * 8 + lr;
            gload_lds16((const char*)(A  + (size_t)(bm + row) * K + kt*64) + sslot,
                        (char*)As + i*4096 + wave*1024);
            gload_lds16((const char*)(Bt + (size_t)(bn + row) * K + kt*64) + sslot,
                        (char*)Bs + i*4096 + wave*1024);
        }
        __syncthreads();
#pragma unroll
        for (int ks = 0; ks < 2; ++ks) {
            v8s af[4], bfr[4];
#pragma unroll
            for (int mf = 0; mf < 4; ++mf) {
                int row = wm + mf*16 + lo;
                af[mf] = *reinterpret_cast<const v8s*>(reinterpret_cast<const char*>(As)
                           + row*128 + ((ks*64 + hi*16) ^ ((row & 7) << 4)));
            }
#pragma unroll
            for (int nf = 0; nf < 4; ++nf) {
                int row = wn + nf*16 + lo;
                bfr[nf] = *reinterpret_cast<const v8s*>(reinterpret_cast<const char*>(Bs)
                           + row*128 + ((ks*64 + hi*16) ^ ((row & 7) << 4)));
            }
#pragma unroll
            for (int mf = 0; mf < 4; ++mf)
#pragma unroll
                for (int nf = 0; nf < 4; ++nf)
                    acc[mf][nf] = __builtin_amdgcn_mfma_f32_16x16x32_bf16(af[mf], bfr[nf], acc[mf][nf], 0, 0, 0);
        }
    }
    // epilogue: C/D layout col=lane&15, row=(lane>>4)*4+reg
#pragma unroll
    for (int nf = 0; nf < 4; ++nf) {
        int col = bn + wn + nf*16 + lo;
#pragma unroll
        for (int mf = 0; mf < 4; ++mf) {
#pragma unroll
            for (int j = 0; j < 4; ++j) {
                int grow = bm + wm + mf*16 + hi*4 + j;
                float acv = acc[mf][nf][j];
                if (MODE == 1) {
                    reinterpret_cast<float*>(Cout)[(size_t)grow * Nout + col] = acv + bias1[col];
                } else if (MODE == 2) {
                    // grow = kvh*64+d in [0,256); col = b*2048+n
                    float val = acv + bias1[grow];
                    reinterpret_cast<short*>(Cout)[((size_t)(col >> 11) * 256 + grow) * 2048 + (col & 2047)] = f2bf(val);
                } else { // MODE 3
                    int b = grow >> 11, n = grow & 2047;
                    if (col < 1024) {
                        int hh = col >> 6, d = col & 63;
                        float val = (acv + bias1[col]) * QSCALE;
                        reinterpret_cast<short*>(Cout)[((size_t)(b * HEADS + hh) * SEQ + n) * HD + d] = f2bf(val);
                    } else {
                        int cc = col - 1024;
                        int kvh = cc >> 6, d = cc & 63;
                        float val = acv + bias2[cc];
                        reinterpret_cast<short*>(Cout)[4194304 + ((size_t)(b * KVH + kvh) * SEQ + n) * HD + d] = f2bf(val);
                    }
                }
            }
        }
    }
}

// ---------------- flash attention: GQA-shared LDS K/V, KVBLK=128, swapped-operand ----------------
// Grid: 512 blocks (b,kvh,q-tile) x 256 threads (4 waves = 4 GQA heads sharing K/V).
// Per iteration: stage NEXT 128-kv tile (32 KB, global_load_lds, double-buffered),
// compute 4 sub-tiles of 32 kv from current buffer, ONE barrier (16 drains total vs
// 64 at KVBLK=32 — the round-7 stall).
// Swizzle s(r) = (r&7) ^ ((r&8)>>1) on K slots / V chunks (applied to stage SOURCE and
// read — rule #21); bit-3 term makes residual conflicts 2-way (free, m136).
__global__ __launch_bounds__(256, 4)
void k_attn(const short* __restrict__ Q, const short* __restrict__ K,
            const short* __restrict__ Vt, short* __restrict__ AO) {
    __shared__ int4 KbL[2][1024];   // 2 x 16KB: [128 kv][8 slot16]
    __shared__ int4 VbL[2][1024];   // 2 x 16KB: [64 d][16 chunk16]
    const int tid  = threadIdx.x;
    const int lane = tid & 63;
    const int w    = tid >> 6;              // wave = head index within GQA group
    const int l31 = lane & 31, hi2 = (lane >> 5) & 1;
    const int id  = blockIdx.x;
    const int g   = id & 7;                 // (b, kvh) group -> XCD locality
    const int b   = g >> 2, kvh = g & 3;
    const int qt  = id >> 3;                // 0..63
    const int h   = kvh * 4 + w;
    const int q0  = qt * 32;

    const char* Kg = (const char*)(K  + (size_t)(b * KVH + kvh) * SEQ * HD);
    const char* Vg = (const char*)(Vt + (size_t)(b * KVH + kvh) * HD * SEQ);
    const short* Qb = Q + ((size_t)(b * HEADS + h) * SEQ + q0) * HD;

    // Q fragments (B-operand): col q = l31, k(d) = 16c + 8*hi2 + j
    v8s qf[4];
#pragma unroll
    for (int c = 0; c < 4; ++c)
        qf[c] = *reinterpret_cast<const v8s*>(Qb + (size_t)l31 * HD + c * 16 + hi2 * 8);

    f32x16 acc0 = {}, acc1 = {};   // O^T rows d 0-31 / 32-63, col q = l31
    float mrun = -1e30f, lsum = 0.f;
    const int sr = (l31 & 7) ^ ((l31 & 8) >> 1);    // read swizzle (rows l31 / 32+l31)

    auto stage = [&](int bi, int T) {
#pragma unroll
        for (int i = 0; i < 4; ++i) {
            int r  = w * 32 + i * 8 + (lane >> 3);                  // K row 0..127
            int ks = ((lane & 7) ^ (r & 7) ^ ((r & 8) >> 1)) << 4;
            gload_lds16(Kg + (size_t)T * 16384 + (size_t)r * 128 + ks,
                        (char*)KbL[bi] + w * 4096 + i * 1024);
            int d  = w * 16 + i * 4 + (lane >> 4);                  // V row 0..63
            int cs = (((lane & 15) ^ (d & 7) ^ ((d & 8) >> 1))) << 4;
            gload_lds16(Vg + (size_t)d * 4096 + (size_t)T * 256 + cs,
                        (char*)VbL[bi] + w * 4096 + i * 1024);
        }
    };

    stage(0, 0);
    __syncthreads();
    int cur = 0;
    for (int T = 0; T < SEQ / 128; ++T) {
        if (T + 1 < SEQ / 128) stage(cur ^ 1, T + 1);   // hides under compute; barrier drains
        const char* Kl = (const char*)KbL[cur];
        const char* Vl = (const char*)VbL[cur];
#pragma unroll
        for (int st = 0; st < 4; ++st) {
            // S^T = K.Q^T  (rows st*32..st*32+31 of the tile)
            f32x16 s = {};
#pragma unroll
            for (int c = 0; c < 4; ++c) {
                v8s kf = *reinterpret_cast<const v8s*>(
                    Kl + (st*32 + l31) * 128 + (((2*c + hi2) ^ sr) << 4));
                s = __builtin_amdgcn_mfma_f32_32x32x16_bf16(kf, qf[c], s, 0, 0, 0);
            }
            // max over this sub-tile's 32 kv (16 in-lane + cross-half)
            float m0 = fmaxf(fmaxf(s[0],  s[1]),  fmaxf(s[2],  s[3]));
            float m1 = fmaxf(fmaxf(s[4],  s[5]),  fmaxf(s[6],  s[7]));
            float m2 = fmaxf(fmaxf(s[8],  s[9]),  fmaxf(s[10], s[11]));
            float m3 = fmaxf(fmaxf(s[12], s[13]), fmaxf(s[14], s[15]));
            float pmax = fmaxf(fmaxf(m0, m1), fmaxf(m2, m3));
            pmax = fmaxf(pmax, __shfl_xor(pmax, 32));
            // defer-max (T13): only rescale when max grew by > 8 (log2 domain)
            if (!__all(pmax <= mrun + 8.f)) {
                float mnew = fmaxf(mrun, pmax);
                float sc = exp2f(mrun - mnew);
#pragma unroll
                for (int r = 0; r < 16; ++r) { acc0[r] *= sc; acc1[r] *= sc; }
                lsum *= sc;
                mrun = mnew;
            }
#pragma unroll
            for (int r = 0; r < 16; ++r) s[r] = exp2f(s[r] - mrun);   // p in-place
            float a0 = (s[0] + s[1]) + (s[2]  + s[3]);
            float a1 = (s[4] + s[5]) + (s[6]  + s[7]);
            float a2 = (s[8] + s[9]) + (s[10] + s[11]);
            float a3 = (s[12]+ s[13])+ (s[14] + s[15]);
            float ls = (a0 + a1) + (a2 + a3);
            lsum += ls + __shfl_xor(ls, 32);

            // pack p -> bf16 pairs; pk_i = (p[2i] low, p[2i+1] high)
            int pk[8];
#pragma unroll
            for (int i = 0; i < 8; ++i) {
                int r;
                asm("v_cvt_pk_bf16_f32 %0, %1, %2" : "=v"(r) : "v"(s[2*i]), "v"(s[2*i+1]));
                pk[i] = r;
            }
            // half-exchange: B-operand slot j must hold kv = 16*kc + 8*hi2 + j
            int u[8];
#pragma unroll
            for (int i = 0; i < 2; ++i) {
                int p0 = pk[4*i+0], p1 = pk[4*i+1], p2 = pk[4*i+2], p3 = pk[4*i+3];
                int o0 = __shfl_xor(p0, 32), o1 = __shfl_xor(p1, 32);
                int o2 = __shfl_xor(p2, 32), o3 = __shfl_xor(p3, 32);
                u[4*i+0] = hi2 ? o2 : p0;
                u[4*i+1] = hi2 ? o3 : p1;
                u[4*i+2] = hi2 ? p2 : o0;
                u[4*i+3] = hi2 ? p3 : o1;
            }
            union { int i4[4]; v8s v; } pb0, pb1;
            pb0.i4[0] = u[0]; pb0.i4[1] = u[1]; pb0.i4[2] = u[2]; pb0.i4[3] = u[3];
            pb1.i4[0] = u[4]; pb1.i4[1] = u[5]; pb1.i4[2] = u[6]; pb1.i4[3] = u[7];

            // O^T += V^T-chunk . P^T  (A row = d, k = kv = 8*hi2+j)
            // global chunk = st*4 + 2*kc + hi2; lds chunk = g ^ sr
            {
                v8s vf0 = *reinterpret_cast<const v8s*>(Vl + l31 * 256        + (((st*4     + hi2) ^ sr) << 4));
                acc0 = __builtin_amdgcn_mfma_f32_32x32x16_bf16(vf0, pb0.v, acc0, 0, 0, 0);
                v8s vf1 = *reinterpret_cast<const v8s*>(Vl + (32 + l31) * 256 + (((st*4     + hi2) ^ sr) << 4));
                acc1 = __builtin_amdgcn_mfma_f32_32x32x16_bf16(vf1, pb0.v, acc1, 0, 0, 0);
                v8s vf2 = *reinterpret_cast<const v8s*>(Vl + l31 * 256        + (((st*4 + 2 + hi2) ^ sr) << 4));
                acc0 = __builtin_amdgcn_mfma_f32_32x32x16_bf16(vf2, pb1.v, acc0, 0, 0, 0);
                v8s vf3 = *reinterpret_cast<const v8s*>(Vl + (32 + l31) * 256 + (((st*4 + 2 + hi2) ^ sr) << 4));
                acc1 = __builtin_amdgcn_mfma_f32_32x32x16_bf16(vf3, pb1.v, acc1, 0, 0, 0);
            }
        }
        __syncthreads();   // drains next-tile stage (hidden under 4 sub-tiles) + read-fence
        cur ^= 1;
    }

    // epilogue: lane holds q = q0+l31; d = 8*rg + 4*hi2 + i (+32 for acc1)
    float rinv = 1.f / lsum;
    short* Ao = AO + ((size_t)(b * SEQ + q0 + l31)) * DIM + h * HD;
#pragma unroll
    for (int rg = 0; rg < 4; ++rg) {
        short4 st0, st1;
        st0.x = f2bf(acc0[rg*4+0] * rinv); st0.y = f2bf(acc0[rg*4+1] * rinv);
        st0.z = f2bf(acc0[rg*4+2] * rinv); st0.w = f2bf(acc0[rg*4+3] * rinv);
        *reinterpret_cast<short4*>(Ao + rg*8 + hi2*4) = st0;
        st1.x = f2bf(acc1[rg*4+0] * rinv); st1.y = f2bf(acc1[rg*4+1] * rinv);
        st1.z = f2bf(acc1[rg*4+2] * rinv); st1.w = f2bf(acc1[rg*4+3] * rinv);
        *reinterpret_cast<short4*>(Ao + 32 + rg*8 + hi2*4) = st1;
    }
}

extern "C" void kernel_launch(void* const* d_in, const int* in_sizes, int n_in,
                              void* d_out, int out_size, void* d_ws, size_t ws_size,
                              hipStream_t stream) {
    const float* x  = (const float*)d_in[0];
    const float* Wq = (const float*)d_in[1];
    const float* bq = (const float*)d_in[2];
    const float* Wk = (const float*)d_in[3];
    const float* bk = (const float*)d_in[4];
    const float* Wv = (const float*)d_in[5];
    const float* bv = (const float*)d_in[6];
    const float* Wo = (const float*)d_in[7];
    const float* bo = (const float*)d_in[8];
    float* out = (float*)d_out;

    char* w = (char*)d_ws;
    size_t off = 0;
    auto alloc = [&](size_t bytes) { void* p = w + off; off += (bytes + 255) & ~(size_t)255; return p; };
    short* xb   = (short*)alloc((size_t)MTOT * DIM * 2);           // x bf16
    short* WqkT = (short*)alloc((size_t)(DIM + KVH*HD) * DIM * 2); // [1280][1024]
    short* WvT  = (short*)alloc((size_t)(KVH*HD) * DIM * 2);       // [256][1024]
    short* WoT  = (short*)alloc((size_t)DIM * DIM * 2);
    short* QK   = (short*)alloc((size_t)(BATCH*HEADS*SEQ*HD + BATCH*KVH*SEQ*HD) * 2); // Q then K
    short* VtG  = (short*)alloc((size_t)BATCH * KVH * HD * SEQ * 2); // V^T [b][kvh*64+d][n]
    short* AO   = (short*)alloc((size_t)MTOT * DIM * 2);           // attn out [B][N][H*D]

    short* Qh = QK;
    short* Kh = QK + (size_t)BATCH * HEADS * SEQ * HD;  // == QK + 4194304

    k_cvt<<<dim3((MTOT * DIM / 4 + 255) / 256), dim3(256), 0, stream>>>(x, xb, MTOT * DIM / 4);
    k_transpose_all<<<dim3(32, 32, 4), dim3(256), 0, stream>>>(Wq, Wk, Wv, Wo, WqkT, WvT, WoT);

    // fused Q+K projection (Nout = 1280)
    k_gemm<3><<<dim3(MTOT/128, (DIM + KVH*HD)/128), dim3(256), 0, stream>>>(
        xb, WqkT, bq, bk, (void*)QK, DIM, DIM + KVH*HD);
    // V^T = Wv^T . x^T  (M=256, N=4096) — emits V already transposed
    k_gemm<2><<<dim3((KVH*HD)/128, MTOT/128), dim3(256), 0, stream>>>(
        WvT, xb, bv, nullptr, (void*)VtG, DIM, MTOT);

    // one block per (b, kvh, 32-row q-tile): 2*4*64 = 512 blocks, 4 waves = 4 GQA heads
    k_attn<<<dim3(BATCH * KVH * (SEQ/32)), dim3(256), 0, stream>>>(Qh, Kh, VtG, AO);

    k_gemm<1><<<dim3(MTOT/128, DIM/128), dim3(256), 0, stream>>>(
        AO, WoT, bo, nullptr, (void*)out, DIM, DIM);
}

// Round 9
// 216.763 us; speedup vs baseline: 1.8020x; 1.0860x over previous
//
#include <hip/hip_runtime.h>
#include <hip/hip_bf16.h>
#include <stdint.h>

#define DIM   1024
#define HEADS 16
#define KVH   4
#define HD    64
#define SEQ   2048
#define BATCH 2
#define MTOT  (BATCH*SEQ)   // 4096

// 0.125 (= HD^-0.5) * log2(e): Q is pre-scaled so softmax uses exp2 directly.
#define QSCALE 0.18033688011112042f

typedef __attribute__((ext_vector_type(8)))  short v8s;    // 8 bf16 (4 VGPRs)
typedef __attribute__((ext_vector_type(4)))  float v4f;    // 16x16 accumulator
typedef __attribute__((ext_vector_type(16))) float f32x16; // 32x32 accumulator

static __device__ __forceinline__ short f2bf(float v) {
    __hip_bfloat16 h = __float2bfloat16(v);
    return *reinterpret_cast<short*>(&h);
}

static __device__ __forceinline__ void gload_lds16(const void* g, void* l) {
    __builtin_amdgcn_global_load_lds(
        (const __attribute__((address_space(1))) unsigned int*)g,
        (__attribute__((address_space(3))) unsigned int*)l, 16, 0, 0);
}

// ---------------- f32 -> bf16 convert (vectorized) ----------------
__global__ __launch_bounds__(256) void k_cvt(const float* __restrict__ in,
                                             short* __restrict__ out, int n4) {
    int i = blockIdx.x * 256 + threadIdx.x;
    if (i >= n4) return;
    float4 v = reinterpret_cast<const float4*>(in)[i];
    short4 o;
    o.x = f2bf(v.x); o.y = f2bf(v.y); o.z = f2bf(v.z); o.w = f2bf(v.w);
    reinterpret_cast<short4*>(out)[i] = o;
}

// ---------------- all 4 weight transposes in ONE launch (z picks matrix) ----------------
__global__ __launch_bounds__(256) void k_transpose_all(
        const float* __restrict__ Wq, const float* __restrict__ Wk,
        const float* __restrict__ Wv, const float* __restrict__ Wo,
        short* __restrict__ WqkT, short* __restrict__ WvT, short* __restrict__ WoT) {
    const int z = blockIdx.z;
    const float* W; short* Wt; int rows, cols;
    if      (z == 0) { W = Wq; Wt = WqkT;            rows = DIM; cols = DIM;    }
    else if (z == 1) { W = Wk; Wt = WqkT + DIM*DIM;  rows = DIM; cols = KVH*HD; }
    else if (z == 2) { W = Wv; Wt = WvT;             rows = DIM; cols = KVH*HD; }
    else             { W = Wo; Wt = WoT;             rows = DIM; cols = DIM;    }
    int c0 = blockIdx.x * 32, r0 = blockIdx.y * 32;
    if (c0 >= cols || r0 >= rows) return;
    __shared__ float tile[32][33];
    int tx = threadIdx.x & 31;
    int ty = threadIdx.x >> 5;        // 0..7
#pragma unroll
    for (int i = 0; i < 4; ++i)
        tile[ty + i*8][tx] = W[(size_t)(r0 + ty + i*8) * cols + c0 + tx];
    __syncthreads();
#pragma unroll
    for (int i = 0; i < 4; ++i)
        Wt[(size_t)(c0 + ty + i*8) * rows + r0 + tx] = f2bf(tile[tx][ty + i*8]);
}

// ---------------- GEMM: C[M][Nout] = A[M][K] * Bt[Nout][K]^T + bias ----------------
// BM=64, BN=128 tiles (grids 640/128/512 blocks -> 2-2.5 blocks/CU; the 128x128
// version starved the grid at 1-1.25 blocks/CU = 1 wave/SIMD, ~150 TF effective).
// Staging via global_load_lds (linear LDS dest; swizzled layout kept by
// INVERSE-swizzling the global source slot: LDS[row][s] = G[row][s ^ (row&7)]).
// MODE 1: out f32 row-major [M][Nout]                        (O-projection)
// MODE 2: out bf16 V^T: addr ((col>>11)*256 + grow)*2048 + (col&2047), bias1[grow]
// MODE 3: fused Q+K: col<1024 -> Q [b][h][n][64] * QSCALE (bias1);
//                    col>=1024 -> K [b][kvh][n][64] (bias2); K block at +4194304 elems
template<int MODE>
__global__ __launch_bounds__(256)
void k_gemm(const short* __restrict__ A, const short* __restrict__ Bt,
            const float* __restrict__ bias1, const float* __restrict__ bias2,
            void* __restrict__ Cout, int K, int Nout) {
    __shared__ short As[64 * 64];    // 8 KB
    __shared__ short Bs[128 * 64];   // 16 KB
    const int tid  = threadIdx.x;
    const int lane = tid & 63;
    const int wave = tid >> 6;
    const int bm = blockIdx.x * 64;
    const int bn = blockIdx.y * 128;
    const int wm = (wave >> 1) * 32;       // wave m-half: 2 frags of 16
    const int wn = (wave & 1) * 64;        // wave n-half: 4 frags of 16
    const int lo = lane & 15, hi = lane >> 4;
    const int l8 = lane & 7, lr = lane >> 3;        // staging: slot, row-within-8
    const int sslot = (l8 ^ lr) << 4;               // inverse-swizzled src slot bytes
    v4f acc[2][4] = {};
    const int nkt = K >> 6;
    for (int kt = 0; kt < nkt; ++kt) {
        __syncthreads();
#pragma unroll
        for (int i = 0; i < 2; ++i) {
            int row = i * 32 + wave * 8 + lr;
            gload_lds16((const char*)(A  + (size_t)(bm + row) * K + kt*64) + sslot,
                        (char*)As + i*4096 + wave*1024);
        }
#pragma unroll
        for (int i = 0; i < 4; ++i) {
            int row = i * 32 + wave * 8 + lr;
            gload_lds16((const char*)(Bt + (size_t)(bn + row) * K + kt*64) + sslot,
                        (char*)Bs + i*4096 + wave*1024);
        }
        __syncthreads();
#pragma unroll
        for (int ks = 0; ks < 2; ++ks) {
            v8s af[2], bfr[4];
#pragma unroll
            for (int mf = 0; mf < 2; ++mf) {
                int row = wm + mf*16 + lo;
                af[mf] = *reinterpret_cast<const v8s*>(reinterpret_cast<const char*>(As)
                           + row*128 + ((ks*64 + hi*16) ^ ((row & 7) << 4)));
            }
#pragma unroll
            for (int nf = 0; nf < 4; ++nf) {
                int row = wn + nf*16 + lo;
                bfr[nf] = *reinterpret_cast<const v8s*>(reinterpret_cast<const char*>(Bs)
                           + row*128 + ((ks*64 + hi*16) ^ ((row & 7) << 4)));
            }
#pragma unroll
            for (int mf = 0; mf < 2; ++mf)
#pragma unroll
                for (int nf = 0; nf < 4; ++nf)
                    acc[mf][nf] = __builtin_amdgcn_mfma_f32_16x16x32_bf16(af[mf], bfr[nf], acc[mf][nf], 0, 0, 0);
        }
    }
    // epilogue: C/D layout col=lane&15, row=(lane>>4)*4+reg
#pragma unroll
    for (int nf = 0; nf < 4; ++nf) {
        int col = bn + wn + nf*16 + lo;
#pragma unroll
        for (int mf = 0; mf < 2; ++mf) {
#pragma unroll
            for (int j = 0; j < 4; ++j) {
                int grow = bm + wm + mf*16 + hi*4 + j;
                float acv = acc[mf][nf][j];
                if (MODE == 1) {
                    reinterpret_cast<float*>(Cout)[(size_t)grow * Nout + col] = acv + bias1[col];
                } else if (MODE == 2) {
                    // grow = kvh*64+d in [0,256); col = b*2048+n
                    float val = acv + bias1[grow];
                    reinterpret_cast<short*>(Cout)[((size_t)(col >> 11) * 256 + grow) * 2048 + (col & 2047)] = f2bf(val);
                } else { // MODE 3
                    int b = grow >> 11, n = grow & 2047;
                    if (col < 1024) {
                        int hh = col >> 6, d = col & 63;
                        float val = (acv + bias1[col]) * QSCALE;
                        reinterpret_cast<short*>(Cout)[((size_t)(b * HEADS + hh) * SEQ + n) * HD + d] = f2bf(val);
                    } else {
                        int cc = col - 1024;
                        int kvh = cc >> 6, d = cc & 63;
                        float val = acv + bias2[cc];
                        reinterpret_cast<short*>(Cout)[4194304 + ((size_t)(b * KVH + kvh) * SEQ + n) * HD + d] = f2bf(val);
                    }
                }
            }
        }
    }
}

// ---------------- flash attention: GQA-shared LDS K/V, KVBLK=128, swapped-operand ----------------
// (byte-identical to round 8 — verified; ~84 us, near its structural VALU floor)
__global__ __launch_bounds__(256, 4)
void k_attn(const short* __restrict__ Q, const short* __restrict__ K,
            const short* __restrict__ Vt, short* __restrict__ AO) {
    __shared__ int4 KbL[2][1024];   // 2 x 16KB: [128 kv][8 slot16]
    __shared__ int4 VbL[2][1024];   // 2 x 16KB: [64 d][16 chunk16]
    const int tid  = threadIdx.x;
    const int lane = tid & 63;
    const int w    = tid >> 6;              // wave = head index within GQA group
    const int l31 = lane & 31, hi2 = (lane >> 5) & 1;
    const int id  = blockIdx.x;
    const int g   = id & 7;                 // (b, kvh) group -> XCD locality
    const int b   = g >> 2, kvh = g & 3;
    const int qt  = id >> 3;                // 0..63
    const int h   = kvh * 4 + w;
    const int q0  = qt * 32;

    const char* Kg = (const char*)(K  + (size_t)(b * KVH + kvh) * SEQ * HD);
    const char* Vg = (const char*)(Vt + (size_t)(b * KVH + kvh) * HD * SEQ);
    const short* Qb = Q + ((size_t)(b * HEADS + h) * SEQ + q0) * HD;

    // Q fragments (B-operand): col q = l31, k(d) = 16c + 8*hi2 + j
    v8s qf[4];
#pragma unroll
    for (int c = 0; c < 4; ++c)
        qf[c] = *reinterpret_cast<const v8s*>(Qb + (size_t)l31 * HD + c * 16 + hi2 * 8);

    f32x16 acc0 = {}, acc1 = {};   // O^T rows d 0-31 / 32-63, col q = l31
    float mrun = -1e30f, lsum = 0.f;
    const int sr = (l31 & 7) ^ ((l31 & 8) >> 1);    // read swizzle (rows l31 / 32+l31)

    auto stage = [&](int bi, int T) {
#pragma unroll
        for (int i = 0; i < 4; ++i) {
            int r  = w * 32 + i * 8 + (lane >> 3);                  // K row 0..127
            int ks = ((lane & 7) ^ (r & 7) ^ ((r & 8) >> 1)) << 4;
            gload_lds16(Kg + (size_t)T * 16384 + (size_t)r * 128 + ks,
                        (char*)KbL[bi] + w * 4096 + i * 1024);
            int d  = w * 16 + i * 4 + (lane >> 4);                  // V row 0..63
            int cs = (((lane & 15) ^ (d & 7) ^ ((d & 8) >> 1))) << 4;
            gload_lds16(Vg + (size_t)d * 4096 + (size_t)T * 256 + cs,
                        (char*)VbL[bi] + w * 4096 + i * 1024);
        }
    };

    stage(0, 0);
    __syncthreads();
    int cur = 0;
    for (int T = 0; T < SEQ / 128; ++T) {
        if (T + 1 < SEQ / 128) stage(cur ^ 1, T + 1);   // hides under compute; barrier drains
        const char* Kl = (const char*)KbL[cur];
        const char* Vl = (const char*)VbL[cur];
#pragma unroll
        for (int st = 0; st < 4; ++st) {
            // S^T = K.Q^T  (rows st*32..st*32+31 of the tile)
            f32x16 s = {};
#pragma unroll
            for (int c = 0; c < 4; ++c) {
                v8s kf = *reinterpret_cast<const v8s*>(
                    Kl + (st*32 + l31) * 128 + (((2*c + hi2) ^ sr) << 4));
                s = __builtin_amdgcn_mfma_f32_32x32x16_bf16(kf, qf[c], s, 0, 0, 0);
            }
            // max over this sub-tile's 32 kv (16 in-lane + cross-half)
            float m0 = fmaxf(fmaxf(s[0],  s[1]),  fmaxf(s[2],  s[3]));
            float m1 = fmaxf(fmaxf(s[4],  s[5]),  fmaxf(s[6],  s[7]));
            float m2 = fmaxf(fmaxf(s[8],  s[9]),  fmaxf(s[10], s[11]));
            float m3 = fmaxf(fmaxf(s[12], s[13]), fmaxf(s[14], s[15]));
            float pmax = fmaxf(fmaxf(m0, m1), fmaxf(m2, m3));
            pmax = fmaxf(pmax, __shfl_xor(pmax, 32));
            // defer-max (T13): only rescale when max grew by > 8 (log2 domain)
            if (!__all(pmax <= mrun + 8.f)) {
                float mnew = fmaxf(mrun, pmax);
                float sc = exp2f(mrun - mnew);
#pragma unroll
                for (int r = 0; r < 16; ++r) { acc0[r] *= sc; acc1[r] *= sc; }
                lsum *= sc;
                mrun = mnew;
            }
#pragma unroll
            for (int r = 0; r < 16; ++r) s[r] = exp2f(s[r] - mrun);   // p in-place
            float a0 = (s[0] + s[1]) + (s[2]  + s[3]);
            float a1 = (s[4] + s[5]) + (s[6]  + s[7]);
            float a2 = (s[8] + s[9]) + (s[10] + s[11]);
            float a3 = (s[12]+ s[13])+ (s[14] + s[15]);
            float ls = (a0 + a1) + (a2 + a3);
            lsum += ls + __shfl_xor(ls, 32);

            // pack p -> bf16 pairs; pk_i = (p[2i] low, p[2i+1] high)
            int pk[8];
#pragma unroll
            for (int i = 0; i < 8; ++i) {
                int r;
                asm("v_cvt_pk_bf16_f32 %0, %1, %2" : "=v"(r) : "v"(s[2*i]), "v"(s[2*i+1]));
                pk[i] = r;
            }
            // half-exchange: B-operand slot j must hold kv = 16*kc + 8*hi2 + j
            int u[8];
#pragma unroll
            for (int i = 0; i < 2; ++i) {
                int p0 = pk[4*i+0], p1 = pk[4*i+1], p2 = pk[4*i+2], p3 = pk[4*i+3];
                int o0 = __shfl_xor(p0, 32), o1 = __shfl_xor(p1, 32);
                int o2 = __shfl_xor(p2, 32), o3 = __shfl_xor(p3, 32);
                u[4*i+0] = hi2 ? o2 : p0;
                u[4*i+1] = hi2 ? o3 : p1;
                u[4*i+2] = hi2 ? p2 : o0;
                u[4*i+3] = hi2 ? p3 : o1;
            }
            union { int i4[4]; v8s v; } pb0, pb1;
            pb0.i4[0] = u[0]; pb0.i4[1] = u[1]; pb0.i4[2] = u[2]; pb0.i4[3] = u[3];
            pb1.i4[0] = u[4]; pb1.i4[1] = u[5]; pb1.i4[2] = u[6]; pb1.i4[3] = u[7];

            // O^T += V^T-chunk . P^T  (A row = d, k = kv = 8*hi2+j)
            // global chunk = st*4 + 2*kc + hi2; lds chunk = g ^ sr
            {
                v8s vf0 = *reinterpret_cast<const v8s*>(Vl + l31 * 256        + (((st*4     + hi2) ^ sr) << 4));
                acc0 = __builtin_amdgcn_mfma_f32_32x32x16_bf16(vf0, pb0.v, acc0, 0, 0, 0);
                v8s vf1 = *reinterpret_cast<const v8s*>(Vl + (32 + l31) * 256 + (((st*4     + hi2) ^ sr) << 4));
                acc1 = __builtin_amdgcn_mfma_f32_32x32x16_bf16(vf1, pb0.v, acc1, 0, 0, 0);
                v8s vf2 = *reinterpret_cast<const v8s*>(Vl + l31 * 256        + (((st*4 + 2 + hi2) ^ sr) << 4));
                acc0 = __builtin_amdgcn_mfma_f32_32x32x16_bf16(vf2, pb1.v, acc0, 0, 0, 0);
                v8s vf3 = *reinterpret_cast<const v8s*>(Vl + (32 + l31) * 256 + (((st*4 + 2 + hi2) ^ sr) << 4));
                acc1 = __builtin_amdgcn_mfma_f32_32x32x16_bf16(vf3, pb1.v, acc1, 0, 0, 0);
            }
        }
        __syncthreads();   // drains next-tile stage (hidden under 4 sub-tiles) + read-fence
        cur ^= 1;
    }

    // epilogue: lane holds q = q0+l31; d = 8*rg + 4*hi2 + i (+32 for acc1)
    float rinv = 1.f / lsum;
    short* Ao = AO + ((size_t)(b * SEQ + q0 + l31)) * DIM + h * HD;
#pragma unroll
    for (int rg = 0; rg < 4; ++rg) {
        short4 st0, st1;
        st0.x = f2bf(acc0[rg*4+0] * rinv); st0.y = f2bf(acc0[rg*4+1] * rinv);
        st0.z = f2bf(acc0[rg*4+2] * rinv); st0.w = f2bf(acc0[rg*4+3] * rinv);
        *reinterpret_cast<short4*>(Ao + rg*8 + hi2*4) = st0;
        st1.x = f2bf(acc1[rg*4+0] * rinv); st1.y = f2bf(acc1[rg*4+1] * rinv);
        st1.z = f2bf(acc1[rg*4+2] * rinv); st1.w = f2bf(acc1[rg*4+3] * rinv);
        *reinterpret_cast<short4*>(Ao + 32 + rg*8 + hi2*4) = st1;
    }
}

extern "C" void kernel_launch(void* const* d_in, const int* in_sizes, int n_in,
                              void* d_out, int out_size, void* d_ws, size_t ws_size,
                              hipStream_t stream) {
    const float* x  = (const float*)d_in[0];
    const float* Wq = (const float*)d_in[1];
    const float* bq = (const float*)d_in[2];
    const float* Wk = (const float*)d_in[3];
    const float* bk = (const float*)d_in[4];
    const float* Wv = (const float*)d_in[5];
    const float* bv = (const float*)d_in[6];
    const float* Wo = (const float*)d_in[7];
    const float* bo = (const float*)d_in[8];
    float* out = (float*)d_out;

    char* w = (char*)d_ws;
    size_t off = 0;
    auto alloc = [&](size_t bytes) { void* p = w + off; off += (bytes + 255) & ~(size_t)255; return p; };
    short* xb   = (short*)alloc((size_t)MTOT * DIM * 2);           // x bf16
    short* WqkT = (short*)alloc((size_t)(DIM + KVH*HD) * DIM * 2); // [1280][1024]
    short* WvT  = (short*)alloc((size_t)(KVH*HD) * DIM * 2);       // [256][1024]
    short* WoT  = (short*)alloc((size_t)DIM * DIM * 2);
    short* QK   = (short*)alloc((size_t)(BATCH*HEADS*SEQ*HD + BATCH*KVH*SEQ*HD) * 2); // Q then K
    short* VtG  = (short*)alloc((size_t)BATCH * KVH * HD * SEQ * 2); // V^T [b][kvh*64+d][n]
    short* AO   = (short*)alloc((size_t)MTOT * DIM * 2);           // attn out [B][N][H*D]

    short* Qh = QK;
    short* Kh = QK + (size_t)BATCH * HEADS * SEQ * HD;  // == QK + 4194304

    k_cvt<<<dim3((MTOT * DIM / 4 + 255) / 256), dim3(256), 0, stream>>>(x, xb, MTOT * DIM / 4);
    k_transpose_all<<<dim3(32, 32, 4), dim3(256), 0, stream>>>(Wq, Wk, Wv, Wo, WqkT, WvT, WoT);

    // fused Q+K projection (Nout = 1280): 64 x 10 = 640 blocks
    k_gemm<3><<<dim3(MTOT/64, (DIM + KVH*HD)/128), dim3(256), 0, stream>>>(
        xb, WqkT, bq, bk, (void*)QK, DIM, DIM + KVH*HD);
    // V^T = Wv^T . x^T  (M=256, N=4096): 4 x 32 = 128 blocks
    k_gemm<2><<<dim3((KVH*HD)/64, MTOT/128), dim3(256), 0, stream>>>(
        WvT, xb, bv, nullptr, (void*)VtG, DIM, MTOT);

    // one block per (b, kvh, 32-row q-tile): 2*4*64 = 512 blocks, 4 waves = 4 GQA heads
    k_attn<<<dim3(BATCH * KVH * (SEQ/32)), dim3(256), 0, stream>>>(Qh, Kh, VtG, AO);

    // O-projection: 64 x 8 = 512 blocks
    k_gemm<1><<<dim3(MTOT/64, DIM/128), dim3(256), 0, stream>>>(
        AO, WoT, bo, nullptr, (void*)out, DIM, DIM);
}